// Round 2
// 769.868 us; speedup vs baseline: 1.0369x; 1.0369x over previous
//
#include <hip/hip_runtime.h>
#include <stdint.h>

#define N_NODES 50000
#define N_EDGES 800000
#define EDGE_F  96
#define NODE_F  256
#define GLOB_F  64
#define HIDDEN  1024
#define MLP_IN  608           // 256 + 3*96 + 64 (valid K)
#define KP      640           // K padded to multiple of 64 for 8-phase GEMM1
#define M_PAD   50176         // 196 * 256
#define SCAN_BLOCKS 196       // 196*256 = 50176 >= 50000
#define NT1     10            // KP / 64

typedef __bf16 bf16;
typedef __bf16 bf16x8 __attribute__((ext_vector_type(8)));
typedef float  f32x4  __attribute__((ext_vector_type(4)));

typedef __attribute__((address_space(1))) unsigned int gu32;
typedef __attribute__((address_space(3))) unsigned int lu32;

__device__ __forceinline__ void glds16(const void* g, void* l) {
    __builtin_amdgcn_global_load_lds((const gu32*)g, (lu32*)l, 16, 0, 0);
}

// ---------------- workspace layout (bytes) ----------------
static constexpr size_t H_OFF    = 0;
static constexpr size_t H_BYTES  = (size_t)M_PAD * KP * 2;
static constexpr size_t HID_OFF  = H_OFF + H_BYTES;
static constexpr size_t HID_BYTES= (size_t)M_PAD * HIDDEN * 2;
static constexpr size_t W1T_OFF  = HID_OFF + HID_BYTES;
static constexpr size_t W1T_BYTES= (size_t)HIDDEN * KP * 2;
static constexpr size_t W2T_OFF  = W1T_OFF + W1T_BYTES;
static constexpr size_t W2T_BYTES= (size_t)NODE_F * HIDDEN * 2;
static constexpr size_t DEG_OFF  = W2T_OFF + W2T_BYTES;
static constexpr size_t DEG_BYTES= 200192;
static constexpr size_t CUR_OFF  = DEG_OFF + DEG_BYTES;
static constexpr size_t CUR_BYTES= 200192;
static constexpr size_t START_OFF= CUR_OFF + CUR_BYTES;
static constexpr size_t START_BYTES = 200192;
static constexpr size_t EIDS_OFF = START_OFF + START_BYTES;
static constexpr size_t EIDS_BYTES = (size_t)N_EDGES * 4;
static constexpr size_t BSUM_OFF = EIDS_OFF + EIDS_BYTES;
static constexpr size_t BSUM_BYTES = 1024;
static constexpr size_t BOFF_OFF = BSUM_OFF + BSUM_BYTES;

// ---------------- CSR build ----------------
__global__ __launch_bounds__(256) void hist_kernel(const int* __restrict__ col,
                                                   int* __restrict__ deg) {
    int e = blockIdx.x * 256 + threadIdx.x;
    if (e < N_EDGES) atomicAdd(&deg[col[e]], 1);
}

__global__ __launch_bounds__(256) void scan_phase1(const int* __restrict__ deg,
                                                   int* __restrict__ start,
                                                   int* __restrict__ bsum) {
    __shared__ int sc[256];
    const int t = threadIdx.x, b = blockIdx.x;
    const int idx = b * 256 + t;
    int v = (idx < N_NODES) ? deg[idx] : 0;
    sc[t] = v;
    __syncthreads();
    for (int off = 1; off < 256; off <<= 1) {
        int add = (t >= off) ? sc[t - off] : 0;
        __syncthreads();
        sc[t] += add;
        __syncthreads();
    }
    if (idx < N_NODES) start[idx] = sc[t] - v;
    if (t == 255) bsum[b] = sc[255];
}

__global__ __launch_bounds__(256) void scan_phase2(int* __restrict__ bsum,
                                                   int* __restrict__ boff,
                                                   int* __restrict__ start) {
    __shared__ int sc[256];
    const int t = threadIdx.x;
    int v = (t < SCAN_BLOCKS) ? bsum[t] : 0;
    sc[t] = v;
    __syncthreads();
    for (int off = 1; off < 256; off <<= 1) {
        int add = (t >= off) ? sc[t - off] : 0;
        __syncthreads();
        sc[t] += add;
        __syncthreads();
    }
    if (t < SCAN_BLOCKS) boff[t] = sc[t] - v;
    if (t == 255) start[N_NODES] = sc[255];
}

__global__ __launch_bounds__(256) void scan_phase3(int* __restrict__ start,
                                                   const int* __restrict__ boff) {
    const int idx = blockIdx.x * 256 + threadIdx.x;
    if (idx < N_NODES) start[idx] += boff[blockIdx.x];
}

__global__ __launch_bounds__(256) void scatter_kernel(const int* __restrict__ col,
                                                      const int* __restrict__ start,
                                                      int* __restrict__ cursor,
                                                      int* __restrict__ eids) {
    int e = blockIdx.x * 256 + threadIdx.x;
    if (e < N_EDGES) {
        int c = col[e];
        int p = start[c] + atomicAdd(&cursor[c], 1);
        eids[p] = e;
    }
}

// ---------------- build H = [x | sum | max | mean | u[batch] | 0-pad] bf16, stride KP ----
#define BH_CHUNK 128
__global__ __launch_bounds__(128) void build_h_kernel(const float* __restrict__ x,
                                                      const float* __restrict__ edge_attr,
                                                      const float* __restrict__ u,
                                                      const int* __restrict__ batch,
                                                      const int* __restrict__ start,
                                                      const int* __restrict__ eids,
                                                      bf16* __restrict__ H) {
    const int n = blockIdx.x;
    const int t = threadIdx.x;
    bf16* row = H + (size_t)n * KP;
    if (n >= N_NODES) {
        for (int c = t; c < KP; c += 128) row[c] = (bf16)0.0f;
        return;
    }
    if (t < 64) {
        float4 v = ((const float4*)(x + (size_t)n * NODE_F))[t];
        row[t * 4 + 0] = (bf16)v.x;
        row[t * 4 + 1] = (bf16)v.y;
        row[t * 4 + 2] = (bf16)v.z;
        row[t * 4 + 3] = (bf16)v.w;
    } else {
        int g = batch[n];
        row[544 + (t - 64)] = (bf16)u[g * GLOB_F + (t - 64)];
    }
    if (t >= 96) row[608 + (t - 96)] = (bf16)0.0f;   // K pad columns

    __shared__ int se[BH_CHUNK];
    const int s0 = start[n], s1 = start[n + 1];
    float sm = 0.0f, mx = -3.0e38f;
    for (int base = s0; base < s1; base += BH_CHUNK) {
        const int cnt = min(BH_CHUNK, s1 - base);
        __syncthreads();
        if (t < cnt) se[t] = eids[base + t];
        __syncthreads();
        if (t < EDGE_F) {
            int i = 0;
            for (; i + 8 <= cnt; i += 8) {
                float v0 = edge_attr[(size_t)se[i + 0] * EDGE_F + t];
                float v1 = edge_attr[(size_t)se[i + 1] * EDGE_F + t];
                float v2 = edge_attr[(size_t)se[i + 2] * EDGE_F + t];
                float v3 = edge_attr[(size_t)se[i + 3] * EDGE_F + t];
                float v4 = edge_attr[(size_t)se[i + 4] * EDGE_F + t];
                float v5 = edge_attr[(size_t)se[i + 5] * EDGE_F + t];
                float v6 = edge_attr[(size_t)se[i + 6] * EDGE_F + t];
                float v7 = edge_attr[(size_t)se[i + 7] * EDGE_F + t];
                sm += ((v0 + v1) + (v2 + v3)) + ((v4 + v5) + (v6 + v7));
                float m01 = fmaxf(v0, v1), m23 = fmaxf(v2, v3);
                float m45 = fmaxf(v4, v5), m67 = fmaxf(v6, v7);
                mx = fmaxf(mx, fmaxf(fmaxf(m01, m23), fmaxf(m45, m67)));
            }
            for (; i + 2 <= cnt; i += 2) {
                float v0 = edge_attr[(size_t)se[i + 0] * EDGE_F + t];
                float v1 = edge_attr[(size_t)se[i + 1] * EDGE_F + t];
                sm += v0 + v1;
                mx = fmaxf(mx, fmaxf(v0, v1));
            }
            if (i < cnt) {
                float v = edge_attr[(size_t)se[i] * EDGE_F + t];
                sm += v;
                mx = fmaxf(mx, v);
            }
        }
    }
    if (t < EDGE_F) {
        int d = s1 - s0;
        if (d == 0) mx = 0.0f;
        float mean = sm / fmaxf((float)d, 1.0f);
        row[256 + t] = (bf16)sm;
        row[352 + t] = (bf16)mx;
        row[448 + t] = (bf16)mean;
    }
}

// ---------------- transpose: W [K][N] f32 -> Wt [N][Kpad] bf16 (zero-fill k>=K) ----------
__global__ __launch_bounds__(256) void transpose_kernel(const float* __restrict__ W,
                                                        bf16* __restrict__ Wt,
                                                        int K, int N, int Kpad) {
    __shared__ float tile[32][33];
    const int tx = threadIdx.x & 31, ty = threadIdx.x >> 5;   // 32 x 8
    const int n0 = blockIdx.x * 32, k0 = blockIdx.y * 32;
    if (k0 < K) {
#pragma unroll
        for (int r = 0; r < 4; r++)
            tile[ty + 8 * r][tx] = W[(size_t)(k0 + ty + 8 * r) * N + (n0 + tx)];
    }
    __syncthreads();
#pragma unroll
    for (int r = 0; r < 4; r++)
        Wt[(size_t)(n0 + ty + 8 * r) * Kpad + (k0 + tx)] =
            (k0 < K) ? (bf16)tile[tx][ty + 8 * r] : (bf16)0.0f;
}

// ---------------- GEMM1: hid = relu(H @ W1 + b1) --------------------------------
// 256x256 tile, BK=64, 512 threads (2Mx4N waves, 128x64 per wave), 8-phase-style
// schedule: XOR-swizzled LDS (pre-swizzled global src + linear glds dest, T2),
// counted vmcnt (T3/T4), setprio around MFMA clusters (T5).
#define VMC(n) asm volatile("s_waitcnt vmcnt(" #n ")" ::: "memory")
#define LGK0   asm volatile("s_waitcnt lgkmcnt(0)" ::: "memory")
#define BARR   __builtin_amdgcn_s_barrier()

__global__ __launch_bounds__(512) void gemm1_kernel(const bf16* __restrict__ H,
                                                    const bf16* __restrict__ Wt,
                                                    const float* __restrict__ b1,
                                                    bf16* __restrict__ hid) {
    __shared__ __align__(16) bf16 As[2][256 * 64];
    __shared__ __align__(16) bf16 Bs[2][256 * 64];
    const int t = threadIdx.x;
    const int wave = t >> 6, lane = t & 63;
    const int quad = lane >> 4, l16 = lane & 15;
    const int wr = wave >> 2;          // 0..1 : M
    const int wc = wave & 3;           // 0..3 : N
    const int bn = blockIdx.x, bm = blockIdx.y;

    f32x4 acc[8][4] = {};
    bf16x8 a[4][2], b[2][2];

    // staging: LDS dest is linear (t*16 per half), global source pre-swizzled
    const int srow = t >> 3;                               // 0..63
    const int scb  = (((t & 7) ^ (srow & 7)) << 4);        // swizzled col-byte
    const char* Ag = (const char*)H  + (size_t)(bm * 256) * (KP * 2);
    const char* Bg = (const char*)Wt + (size_t)(bn * 256) * (KP * 2);
    char* AsB = (char*)&As[0][0];
    char* BsB = (char*)&Bs[0][0];

    // fragment reads: physical = row*128 + (colbyte ^ ((row&7)<<4)); row&7 == l16&7
    const int swzl = (l16 & 7) << 4;
    const int col0 = (quad * 16) ^ swzl;                   // kh = 0
    const int col1 = (64 + quad * 16) ^ swzl;              // kh = 1

#define STG_A(buf, h, kt) do { \
    const char* _s = Ag + (size_t)((h) * 128) * (KP * 2) + (size_t)(kt) * 128; \
    char* _d = AsB + (buf) * 32768 + (h) * 16384 + t * 16; \
    glds16(_s + (size_t)srow * (KP * 2) + scb, _d); \
    glds16(_s + (size_t)(srow + 64) * (KP * 2) + scb, _d + 8192); \
} while (0)
#define STG_B(buf, h, kt) do { \
    const char* _s = Bg + (size_t)((h) * 128) * (KP * 2) + (size_t)(kt) * 128; \
    char* _d = BsB + (buf) * 32768 + (h) * 16384 + t * 16; \
    glds16(_s + (size_t)srow * (KP * 2) + scb, _d); \
    glds16(_s + (size_t)(srow + 64) * (KP * 2) + scb, _d + 8192); \
} while (0)
#define LDA(cbase, mq) do { \
    _Pragma("unroll") for (int i = 0; i < 4; ++i) { \
        const char* _p = (cbase) + (size_t)((mq) * 128 + wr * 64 + i * 16 + l16) * 128; \
        a[i][0] = *(const bf16x8*)(_p + col0); \
        a[i][1] = *(const bf16x8*)(_p + col1); \
    } } while (0)
#define LDB(cbase, nq) do { \
    _Pragma("unroll") for (int j = 0; j < 2; ++j) { \
        const char* _p = (cbase) + (size_t)((nq) * 128 + wc * 32 + j * 16 + l16) * 128; \
        b[j][0] = *(const bf16x8*)(_p + col0); \
        b[j][1] = *(const bf16x8*)(_p + col1); \
    } } while (0)
#define MMAQ(mq, nq) do { \
    __builtin_amdgcn_s_setprio(1); \
    _Pragma("unroll") for (int i = 0; i < 4; ++i) \
    _Pragma("unroll") for (int j = 0; j < 2; ++j) { \
        acc[(mq)*4+i][(nq)*2+j] = __builtin_amdgcn_mfma_f32_16x16x32_bf16(a[i][0], b[j][0], acc[(mq)*4+i][(nq)*2+j], 0, 0, 0); \
        acc[(mq)*4+i][(nq)*2+j] = __builtin_amdgcn_mfma_f32_16x16x32_bf16(a[i][1], b[j][1], acc[(mq)*4+i][(nq)*2+j], 0, 0, 0); \
    } \
    __builtin_amdgcn_s_setprio(0); \
} while (0)

    // prologue: stage tile 0 in consumption order A0,B0,B1,A1  (8 loads/thread)
    STG_A(0, 0, 0);
    STG_B(0, 0, 0);
    STG_B(0, 1, 0);
    STG_A(0, 1, 0);
    VMC(4);              // A0,B0 landed
    BARR;

    // steady: per tile, stagings for kt+1 issued in order A0,B0,B1,A1;
    // FIFO ledger (2 loads/staging): enter with {B1,A1}=4 outstanding.
    // P1 +A0' -> 6, vmcnt(4) retires B1 | P2 +B0' -> 6, vmcnt(4) retires A1
    // P3 +B1' -> 6, no wait             | P4 +A1' -> 8, vmcnt(4) retires A0',B0'
#pragma unroll 1
    for (int kt = 0; kt < NT1 - 1; ++kt) {
        const int c = kt & 1, o = c ^ 1;
        const char* Ac = AsB + c * 32768;
        const char* Bc = BsB + c * 32768;
        // P1: Q(0,0)
        LDA(Ac, 0); LDB(Bc, 0);
        STG_A(o, 0, kt + 1);
        VMC(4); BARR; LGK0;
        MMAQ(0, 0); BARR;
        // P2: Q(0,1)
        LDB(Bc, 1);
        STG_B(o, 0, kt + 1);
        VMC(4); BARR; LGK0;
        MMAQ(0, 1); BARR;
        // P3: Q(1,1)
        LDA(Ac, 1);
        STG_B(o, 1, kt + 1);
        BARR; LGK0;
        MMAQ(1, 1); BARR;
        // P4: Q(1,0)  (B0 still resident)
        LDB(Bc, 0);
        STG_A(o, 1, kt + 1);
        VMC(4); BARR; LGK0;
        MMAQ(1, 0); BARR;
    }
    {   // last tile: no staging; drain B1 then A1
        const int c = (NT1 - 1) & 1;
        const char* Ac = AsB + c * 32768;
        const char* Bc = BsB + c * 32768;
        LDA(Ac, 0); LDB(Bc, 0); VMC(2); BARR; LGK0; MMAQ(0, 0); BARR;
        LDB(Bc, 1);             VMC(0); BARR; LGK0; MMAQ(0, 1); BARR;
        LDA(Ac, 1);                     BARR; LGK0; MMAQ(1, 1); BARR;
        LDB(Bc, 0);                           LGK0; MMAQ(1, 0);
    }

#pragma unroll
    for (int m = 0; m < 8; ++m) {
        const int mq = m >> 2, i = m & 3;
        const int row0 = bm * 256 + mq * 128 + wr * 64 + i * 16 + quad * 4;
#pragma unroll
        for (int n = 0; n < 4; ++n) {
            const int nq = n >> 1, j = n & 1;
            const int col = bn * 256 + nq * 128 + wc * 32 + j * 16 + l16;
            const float bias = b1[col];
#pragma unroll
            for (int r = 0; r < 4; ++r) {
                float v = acc[m][n][r] + bias;
                v = fmaxf(v, 0.0f);
                hid[(size_t)(row0 + r) * HIDDEN + col] = (bf16)v;
            }
        }
    }
#undef STG_A
#undef STG_B
#undef LDA
#undef LDB
#undef MMAQ
}

// ---------------- GEMM2: out = hid @ W2 + b2 + x, fp32 out (128^2 m97-structure) ----
__global__ __launch_bounds__(256) void gemm2_kernel(const bf16* __restrict__ Hd,
                                                    const bf16* __restrict__ Wt,
                                                    const float* __restrict__ b2,
                                                    const float* __restrict__ x,
                                                    float* __restrict__ out) {
    __shared__ __align__(16) bf16 As[128 * 32];
    __shared__ __align__(16) bf16 Bs[128 * 32];
    const int t = threadIdx.x;
    const int wave = t >> 6, lane = t & 63;
    const int quad = lane >> 4, l16 = lane & 15;
    const int wm = (wave & 1) << 6, wn = (wave >> 1) << 6;
    const int bm = blockIdx.x, bn = blockIdx.y;

    f32x4 acc[4][4] = {};

    const char* Ag = (const char*)Hd + (size_t)bm * 128 * (HIDDEN * 2);
    const char* Bg = (const char*)Wt + (size_t)bn * 128 * (HIDDEN * 2);
    const int srow = t >> 2, scc = t & 3;
    const size_t rowoff = (size_t)srow * (HIDDEN * 2) + scc * 16;
    char* Al = (char*)As + t * 16;
    char* Bl = (char*)Bs + t * 16;

    for (int k0 = 0; k0 < HIDDEN; k0 += 32) {
        __syncthreads();
        const char* a0 = Ag + rowoff + k0 * 2;
        glds16(a0, Al);
        glds16(a0 + (size_t)64 * (HIDDEN * 2), Al + 4096);
        const char* b0 = Bg + rowoff + k0 * 2;
        glds16(b0, Bl);
        glds16(b0 + (size_t)64 * (HIDDEN * 2), Bl + 4096);
        __syncthreads();
        bf16x8 a[4], b[4];
#pragma unroll
        for (int i = 0; i < 4; i++) a[i] = *(const bf16x8*)&As[(wm + i * 16 + l16) * 32 + quad * 8];
#pragma unroll
        for (int i = 0; i < 4; i++) b[i] = *(const bf16x8*)&Bs[(wn + i * 16 + l16) * 32 + quad * 8];
#pragma unroll
        for (int i = 0; i < 4; i++)
#pragma unroll
            for (int j = 0; j < 4; j++)
                acc[i][j] = __builtin_amdgcn_mfma_f32_16x16x32_bf16(a[i], b[j], acc[i][j], 0, 0, 0);
    }
#pragma unroll
    for (int i = 0; i < 4; i++) {
        int row0 = bm * 128 + wm + i * 16 + quad * 4;
#pragma unroll
        for (int j = 0; j < 4; j++) {
            int col = bn * 128 + wn + j * 16 + l16;
            float bias = b2[col];
#pragma unroll
            for (int r = 0; r < 4; r++) {
                int row = row0 + r;
                if (row < N_NODES) {
                    size_t idx = (size_t)row * NODE_F + col;
                    out[idx] = acc[i][j][r] + bias + x[idx];
                }
            }
        }
    }
}

extern "C" void kernel_launch(void* const* d_in, const int* in_sizes, int n_in,
                              void* d_out, int out_size, void* d_ws, size_t ws_size,
                              hipStream_t stream) {
    const float* x         = (const float*)d_in[0];
    const float* edge_attr = (const float*)d_in[1];
    const float* u         = (const float*)d_in[2];
    const float* W1        = (const float*)d_in[3];
    const float* b1        = (const float*)d_in[4];
    const float* W2        = (const float*)d_in[5];
    const float* b2        = (const float*)d_in[6];
    const int*   edge_index= (const int*)d_in[7];
    const int*   batch     = (const int*)d_in[8];
    float*       out       = (float*)d_out;

    char* ws = (char*)d_ws;
    bf16* H    = (bf16*)(ws + H_OFF);
    bf16* hid  = (bf16*)(ws + HID_OFF);
    bf16* W1t  = (bf16*)(ws + W1T_OFF);
    bf16* W2t  = (bf16*)(ws + W2T_OFF);
    int*  deg  = (int*)(ws + DEG_OFF);
    int*  cur  = (int*)(ws + CUR_OFF);
    int*  start= (int*)(ws + START_OFF);
    int*  eids = (int*)(ws + EIDS_OFF);
    int*  bsum = (int*)(ws + BSUM_OFF);
    int*  boff = (int*)(ws + BOFF_OFF);

    const int* col = edge_index + N_EDGES;

    hipMemsetAsync(ws + DEG_OFF, 0, DEG_BYTES + CUR_BYTES, stream);
    hist_kernel<<<(N_EDGES + 255) / 256, 256, 0, stream>>>(col, deg);
    scan_phase1<<<SCAN_BLOCKS, 256, 0, stream>>>(deg, start, bsum);
    scan_phase2<<<1, 256, 0, stream>>>(bsum, boff, start);
    scan_phase3<<<SCAN_BLOCKS, 256, 0, stream>>>(start, boff);
    scatter_kernel<<<(N_EDGES + 255) / 256, 256, 0, stream>>>(col, start, cur, eids);
    build_h_kernel<<<M_PAD, 128, 0, stream>>>(x, edge_attr, u, batch, start, eids, H);
    transpose_kernel<<<dim3(HIDDEN / 32, KP / 32), 256, 0, stream>>>(W1, W1t, MLP_IN, HIDDEN, KP);
    transpose_kernel<<<dim3(NODE_F / 32, HIDDEN / 32), 256, 0, stream>>>(W2, W2t, HIDDEN, NODE_F, HIDDEN);
    gemm1_kernel<<<dim3(HIDDEN / 256, M_PAD / 256), 512, 0, stream>>>(H, W1t, b1, hid);
    gemm2_kernel<<<dim3(391, 2), 256, 0, stream>>>(hid, W2t, b2, x, out);
}

// Round 3
// 763.580 us; speedup vs baseline: 1.0454x; 1.0082x over previous
//
#include <hip/hip_runtime.h>
#include <stdint.h>

#define N_NODES 50000
#define N_EDGES 800000
#define EDGE_F  96
#define NODE_F  256
#define GLOB_F  64
#define HIDDEN  1024
#define MLP_IN  608           // 256 + 3*96 + 64 (valid K)
#define KP      640           // K padded to multiple of 64 for 8-phase GEMM1
#define M_PAD   50176         // 196 * 256
#define SCAN_BLOCKS 196       // 196*256 = 50176 >= 50000
#define NT1     10            // KP / 64
#define NT2     16            // HIDDEN / 64

typedef __bf16 bf16;
typedef __bf16 bf16x4 __attribute__((ext_vector_type(4)));
typedef __bf16 bf16x8 __attribute__((ext_vector_type(8)));
typedef float  f32x4  __attribute__((ext_vector_type(4)));

typedef __attribute__((address_space(1))) unsigned int gu32;
typedef __attribute__((address_space(3))) unsigned int lu32;

__device__ __forceinline__ void glds16(const void* g, void* l) {
    __builtin_amdgcn_global_load_lds((const gu32*)g, (lu32*)l, 16, 0, 0);
}

// ---------------- workspace layout (bytes) ----------------
static constexpr size_t H_OFF    = 0;
static constexpr size_t H_BYTES  = (size_t)M_PAD * KP * 2;
static constexpr size_t HID_OFF  = H_OFF + H_BYTES;
static constexpr size_t HID_BYTES= (size_t)M_PAD * HIDDEN * 2;
static constexpr size_t W1T_OFF  = HID_OFF + HID_BYTES;
static constexpr size_t W1T_BYTES= (size_t)HIDDEN * KP * 2;
static constexpr size_t W2T_OFF  = W1T_OFF + W1T_BYTES;
static constexpr size_t W2T_BYTES= (size_t)NODE_F * HIDDEN * 2;
static constexpr size_t DEG_OFF  = W2T_OFF + W2T_BYTES;
static constexpr size_t DEG_BYTES= 200192;
static constexpr size_t CUR_OFF  = DEG_OFF + DEG_BYTES;
static constexpr size_t CUR_BYTES= 200192;
static constexpr size_t START_OFF= CUR_OFF + CUR_BYTES;
static constexpr size_t START_BYTES = 200192;
static constexpr size_t EIDS_OFF = START_OFF + START_BYTES;
static constexpr size_t EIDS_BYTES = (size_t)N_EDGES * 4;
static constexpr size_t BSUM_OFF = EIDS_OFF + EIDS_BYTES;
static constexpr size_t BSUM_BYTES = 1024;
static constexpr size_t BOFF_OFF = BSUM_OFF + BSUM_BYTES;

// ---------------- CSR build ----------------
__global__ __launch_bounds__(256) void hist_kernel(const int* __restrict__ col,
                                                   int* __restrict__ deg) {
    int e = blockIdx.x * 256 + threadIdx.x;
    if (e < N_EDGES) atomicAdd(&deg[col[e]], 1);
}

__global__ __launch_bounds__(256) void scan_phase1(const int* __restrict__ deg,
                                                   int* __restrict__ start,
                                                   int* __restrict__ bsum) {
    __shared__ int sc[256];
    const int t = threadIdx.x, b = blockIdx.x;
    const int idx = b * 256 + t;
    int v = (idx < N_NODES) ? deg[idx] : 0;
    sc[t] = v;
    __syncthreads();
    for (int off = 1; off < 256; off <<= 1) {
        int add = (t >= off) ? sc[t - off] : 0;
        __syncthreads();
        sc[t] += add;
        __syncthreads();
    }
    if (idx < N_NODES) start[idx] = sc[t] - v;
    if (t == 255) bsum[b] = sc[255];
}

__global__ __launch_bounds__(256) void scan_phase2(int* __restrict__ bsum,
                                                   int* __restrict__ boff,
                                                   int* __restrict__ start) {
    __shared__ int sc[256];
    const int t = threadIdx.x;
    int v = (t < SCAN_BLOCKS) ? bsum[t] : 0;
    sc[t] = v;
    __syncthreads();
    for (int off = 1; off < 256; off <<= 1) {
        int add = (t >= off) ? sc[t - off] : 0;
        __syncthreads();
        sc[t] += add;
        __syncthreads();
    }
    if (t < SCAN_BLOCKS) boff[t] = sc[t] - v;
    if (t == 255) start[N_NODES] = sc[255];
}

__global__ __launch_bounds__(256) void scan_phase3(int* __restrict__ start,
                                                   const int* __restrict__ boff) {
    const int idx = blockIdx.x * 256 + threadIdx.x;
    if (idx < N_NODES) start[idx] += boff[blockIdx.x];
}

__global__ __launch_bounds__(256) void scatter_kernel(const int* __restrict__ col,
                                                      const int* __restrict__ start,
                                                      int* __restrict__ cursor,
                                                      int* __restrict__ eids) {
    int e = blockIdx.x * 256 + threadIdx.x;
    if (e < N_EDGES) {
        int c = col[e];
        int p = start[c] + atomicAdd(&cursor[c], 1);
        eids[p] = e;
    }
}

// ---------------- build H = [x | sum | max | mean | u[batch] | 0-pad] bf16, stride KP ----
#define BH_CHUNK 128
__global__ __launch_bounds__(128) void build_h_kernel(const float* __restrict__ x,
                                                      const float* __restrict__ edge_attr,
                                                      const float* __restrict__ u,
                                                      const int* __restrict__ batch,
                                                      const int* __restrict__ start,
                                                      const int* __restrict__ eids,
                                                      bf16* __restrict__ H) {
    const int n = blockIdx.x;
    const int t = threadIdx.x;
    bf16* row = H + (size_t)n * KP;
    if (n >= N_NODES) {
        for (int c = t; c < KP; c += 128) row[c] = (bf16)0.0f;
        return;
    }
    if (t < 64) {
        float4 v = ((const float4*)(x + (size_t)n * NODE_F))[t];
        bf16x4 p;
        p.x = (bf16)v.x; p.y = (bf16)v.y; p.z = (bf16)v.z; p.w = (bf16)v.w;
        *(bf16x4*)(row + t * 4) = p;
    } else {
        int g = batch[n];
        row[544 + (t - 64)] = (bf16)u[g * GLOB_F + (t - 64)];
    }
    if (t >= 96) row[608 + (t - 96)] = (bf16)0.0f;   // K pad columns

    __shared__ int se[BH_CHUNK];
    const int s0 = start[n], s1 = start[n + 1];
    float sm = 0.0f, mx = -3.0e38f;
    for (int base = s0; base < s1; base += BH_CHUNK) {
        const int cnt = min(BH_CHUNK, s1 - base);
        __syncthreads();
        if (t < cnt) se[t] = eids[base + t];
        __syncthreads();
        if (t < EDGE_F) {
            int i = 0;
            for (; i + 8 <= cnt; i += 8) {
                float v0 = edge_attr[(size_t)se[i + 0] * EDGE_F + t];
                float v1 = edge_attr[(size_t)se[i + 1] * EDGE_F + t];
                float v2 = edge_attr[(size_t)se[i + 2] * EDGE_F + t];
                float v3 = edge_attr[(size_t)se[i + 3] * EDGE_F + t];
                float v4 = edge_attr[(size_t)se[i + 4] * EDGE_F + t];
                float v5 = edge_attr[(size_t)se[i + 5] * EDGE_F + t];
                float v6 = edge_attr[(size_t)se[i + 6] * EDGE_F + t];
                float v7 = edge_attr[(size_t)se[i + 7] * EDGE_F + t];
                sm += ((v0 + v1) + (v2 + v3)) + ((v4 + v5) + (v6 + v7));
                float m01 = fmaxf(v0, v1), m23 = fmaxf(v2, v3);
                float m45 = fmaxf(v4, v5), m67 = fmaxf(v6, v7);
                mx = fmaxf(mx, fmaxf(fmaxf(m01, m23), fmaxf(m45, m67)));
            }
            for (; i + 2 <= cnt; i += 2) {
                float v0 = edge_attr[(size_t)se[i + 0] * EDGE_F + t];
                float v1 = edge_attr[(size_t)se[i + 1] * EDGE_F + t];
                sm += v0 + v1;
                mx = fmaxf(mx, fmaxf(v0, v1));
            }
            if (i < cnt) {
                float v = edge_attr[(size_t)se[i] * EDGE_F + t];
                sm += v;
                mx = fmaxf(mx, v);
            }
        }
    }
    if (t < EDGE_F) {
        int d = s1 - s0;
        if (d == 0) mx = 0.0f;
        float mean = sm / fmaxf((float)d, 1.0f);
        row[256 + t] = (bf16)sm;
        row[352 + t] = (bf16)mx;
        row[448 + t] = (bf16)mean;
    }
}

// ---------------- transpose: W [K][N] f32 -> Wt [N][Kpad] bf16 (zero-fill k>=K) ----------
__global__ __launch_bounds__(256) void transpose_kernel(const float* __restrict__ W,
                                                        bf16* __restrict__ Wt,
                                                        int K, int N, int Kpad) {
    __shared__ float tile[32][33];
    const int tx = threadIdx.x & 31, ty = threadIdx.x >> 5;   // 32 x 8
    const int n0 = blockIdx.x * 32, k0 = blockIdx.y * 32;
    if (k0 < K) {
#pragma unroll
        for (int r = 0; r < 4; r++)
            tile[ty + 8 * r][tx] = W[(size_t)(k0 + ty + 8 * r) * N + (n0 + tx)];
    }
    __syncthreads();
#pragma unroll
    for (int r = 0; r < 4; r++)
        Wt[(size_t)(n0 + ty + 8 * r) * Kpad + (k0 + tx)] =
            (k0 < K) ? (bf16)tile[tx][ty + 8 * r] : (bf16)0.0f;
}

// ---------------- shared 8-phase GEMM schedule macros ----------------
#define VMC(n) asm volatile("s_waitcnt vmcnt(" #n ")" ::: "memory")
#define LGK0   asm volatile("s_waitcnt lgkmcnt(0)" ::: "memory")
#define BARR   __builtin_amdgcn_s_barrier()

// ---------------- GEMM1: hid = relu(H @ W1 + b1) --------------------------------
// 256x256 tile, BK=64, 512 threads (2Mx4N waves), 8-phase schedule:
// XOR-swizzled LDS (T2), counted vmcnt (T3/T4), setprio (T5), XCD swizzle (T1).
__global__ __launch_bounds__(512) void gemm1_kernel(const bf16* __restrict__ H,
                                                    const bf16* __restrict__ Wt,
                                                    const float* __restrict__ b1,
                                                    bf16* __restrict__ hid) {
    __shared__ __align__(16) bf16 As[2][256 * 64];
    __shared__ __align__(16) bf16 Bs[2][256 * 64];
    const int t = threadIdx.x;
    const int wave = t >> 6, lane = t & 63;
    const int quad = lane >> 4, l16 = lane & 15;
    const int wr = wave >> 2;          // 0..1 : M
    const int wc = wave & 3;           // 0..3 : N
    // XCD-chunked bijective swizzle: grid 784 = 8 * 98; bn fastest so the 4
    // bn-siblings of one bm (shared 320KB A-panel) land on the same XCD L2.
    const int orig = blockIdx.x;
    const int swz  = (orig & 7) * 98 + (orig >> 3);
    const int bm = swz >> 2, bn = swz & 3;

    f32x4 acc[8][4] = {};
    bf16x8 a[4][2], b[2][2];

    const int srow = t >> 3;                               // 0..63
    const int scb  = (((t & 7) ^ (srow & 7)) << 4);        // swizzled col-byte
    const char* Ag = (const char*)H  + (size_t)(bm * 256) * (KP * 2);
    const char* Bg = (const char*)Wt + (size_t)(bn * 256) * (KP * 2);
    char* AsB = (char*)&As[0][0];
    char* BsB = (char*)&Bs[0][0];

    const int swzl = (l16 & 7) << 4;
    const int col0 = (quad * 16) ^ swzl;                   // kh = 0
    const int col1 = (64 + quad * 16) ^ swzl;              // kh = 1

#define STG_A(buf, h, kt) do { \
    const char* _s = Ag + (size_t)((h) * 128) * (KP * 2) + (size_t)(kt) * 128; \
    char* _d = AsB + (buf) * 32768 + (h) * 16384 + t * 16; \
    glds16(_s + (size_t)srow * (KP * 2) + scb, _d); \
    glds16(_s + (size_t)(srow + 64) * (KP * 2) + scb, _d + 8192); \
} while (0)
#define STG_B(buf, h, kt) do { \
    const char* _s = Bg + (size_t)((h) * 128) * (KP * 2) + (size_t)(kt) * 128; \
    char* _d = BsB + (buf) * 32768 + (h) * 16384 + t * 16; \
    glds16(_s + (size_t)srow * (KP * 2) + scb, _d); \
    glds16(_s + (size_t)(srow + 64) * (KP * 2) + scb, _d + 8192); \
} while (0)
#define LDA(cbase, mq) do { \
    _Pragma("unroll") for (int i = 0; i < 4; ++i) { \
        const char* _p = (cbase) + (size_t)((mq) * 128 + wr * 64 + i * 16 + l16) * 128; \
        a[i][0] = *(const bf16x8*)(_p + col0); \
        a[i][1] = *(const bf16x8*)(_p + col1); \
    } } while (0)
#define LDB(cbase, nq) do { \
    _Pragma("unroll") for (int j = 0; j < 2; ++j) { \
        const char* _p = (cbase) + (size_t)((nq) * 128 + wc * 32 + j * 16 + l16) * 128; \
        b[j][0] = *(const bf16x8*)(_p + col0); \
        b[j][1] = *(const bf16x8*)(_p + col1); \
    } } while (0)
#define MMAQ(mq, nq) do { \
    __builtin_amdgcn_s_setprio(1); \
    _Pragma("unroll") for (int i = 0; i < 4; ++i) \
    _Pragma("unroll") for (int j = 0; j < 2; ++j) { \
        acc[(mq)*4+i][(nq)*2+j] = __builtin_amdgcn_mfma_f32_16x16x32_bf16(a[i][0], b[j][0], acc[(mq)*4+i][(nq)*2+j], 0, 0, 0); \
        acc[(mq)*4+i][(nq)*2+j] = __builtin_amdgcn_mfma_f32_16x16x32_bf16(a[i][1], b[j][1], acc[(mq)*4+i][(nq)*2+j], 0, 0, 0); \
    } \
    __builtin_amdgcn_s_setprio(0); \
} while (0)

    // prologue: stage tile 0 in consumption order A0,B0,B1,A1  (8 loads/thread)
    STG_A(0, 0, 0);
    STG_B(0, 0, 0);
    STG_B(0, 1, 0);
    STG_A(0, 1, 0);
    VMC(4);              // A0,B0 landed
    BARR;

    // steady FIFO ledger (2 loads/staging): enter with {B1,A1}=4 outstanding.
    // P1 +A0' -> 6, vmcnt(4) retires B1 | P2 +B0' -> 6, vmcnt(4) retires A1
    // P3 +B1' -> 6, no wait             | P4 +A1' -> 8, vmcnt(4) retires A0',B0'
#pragma unroll 1
    for (int kt = 0; kt < NT1 - 1; ++kt) {
        const int c = kt & 1, o = c ^ 1;
        const char* Ac = AsB + c * 32768;
        const char* Bc = BsB + c * 32768;
        LDA(Ac, 0); LDB(Bc, 0);
        STG_A(o, 0, kt + 1);
        VMC(4); BARR; LGK0;
        MMAQ(0, 0); BARR;
        LDB(Bc, 1);
        STG_B(o, 0, kt + 1);
        VMC(4); BARR; LGK0;
        MMAQ(0, 1); BARR;
        LDA(Ac, 1);
        STG_B(o, 1, kt + 1);
        BARR; LGK0;
        MMAQ(1, 1); BARR;
        LDB(Bc, 0);
        STG_A(o, 1, kt + 1);
        VMC(4); BARR; LGK0;
        MMAQ(1, 0); BARR;
    }
    {   // last tile: no staging; drain
        const int c = (NT1 - 1) & 1;
        const char* Ac = AsB + c * 32768;
        const char* Bc = BsB + c * 32768;
        LDA(Ac, 0); LDB(Bc, 0); VMC(2); BARR; LGK0; MMAQ(0, 0); BARR;
        LDB(Bc, 1);             VMC(0); BARR; LGK0; MMAQ(0, 1); BARR;
        LDA(Ac, 1);                     BARR; LGK0; MMAQ(1, 1); BARR;
        LDB(Bc, 0);                           LGK0; MMAQ(1, 0);
    }

#pragma unroll
    for (int m = 0; m < 8; ++m) {
        const int mq = m >> 2, i = m & 3;
        const int row0 = bm * 256 + mq * 128 + wr * 64 + i * 16 + quad * 4;
#pragma unroll
        for (int n = 0; n < 4; ++n) {
            const int nq = n >> 1, j = n & 1;
            const int col = bn * 256 + nq * 128 + wc * 32 + j * 16 + l16;
            const float bias = b1[col];
#pragma unroll
            for (int r = 0; r < 4; ++r) {
                float v = acc[m][n][r] + bias;
                v = fmaxf(v, 0.0f);
                hid[(size_t)(row0 + r) * HIDDEN + col] = (bf16)v;
            }
        }
    }
#undef STG_A
#undef STG_B
#undef LDA
#undef LDB
#undef MMAQ
}

// ---------------- GEMM2: out = hid @ W2 + b2 + x, fp32 out ----------------------
// Same 8-phase 256x256 structure; N=256 = exactly one tile (bn==0), NT2=16,
// grid = 196 blocks (one occupancy round at 1 block/CU).
__global__ __launch_bounds__(512) void gemm2_kernel(const bf16* __restrict__ Hd,
                                                    const bf16* __restrict__ Wt,
                                                    const float* __restrict__ b2,
                                                    const float* __restrict__ x,
                                                    float* __restrict__ out) {
    __shared__ __align__(16) bf16 As[2][256 * 64];
    __shared__ __align__(16) bf16 Bs[2][256 * 64];
    const int t = threadIdx.x;
    const int wave = t >> 6, lane = t & 63;
    const int quad = lane >> 4, l16 = lane & 15;
    const int wr = wave >> 2;          // 0..1 : M
    const int wc = wave & 3;           // 0..3 : N
    const int bm = blockIdx.x;

    f32x4 acc[8][4] = {};
    bf16x8 a[4][2], b[2][2];

    const int srow = t >> 3;                               // 0..63
    const int scb  = (((t & 7) ^ (srow & 7)) << 4);        // swizzled col-byte
    const char* Ag = (const char*)Hd + (size_t)(bm * 256) * (HIDDEN * 2);
    const char* Bg = (const char*)Wt;                      // 256 rows x HIDDEN
    char* AsB = (char*)&As[0][0];
    char* BsB = (char*)&Bs[0][0];

    const int swzl = (l16 & 7) << 4;
    const int col0 = (quad * 16) ^ swzl;                   // kh = 0
    const int col1 = (64 + quad * 16) ^ swzl;              // kh = 1

#define STG_A2(buf, h, kt) do { \
    const char* _s = Ag + (size_t)((h) * 128) * (HIDDEN * 2) + (size_t)(kt) * 128; \
    char* _d = AsB + (buf) * 32768 + (h) * 16384 + t * 16; \
    glds16(_s + (size_t)srow * (HIDDEN * 2) + scb, _d); \
    glds16(_s + (size_t)(srow + 64) * (HIDDEN * 2) + scb, _d + 8192); \
} while (0)
#define STG_B2(buf, h, kt) do { \
    const char* _s = Bg + (size_t)((h) * 128) * (HIDDEN * 2) + (size_t)(kt) * 128; \
    char* _d = BsB + (buf) * 32768 + (h) * 16384 + t * 16; \
    glds16(_s + (size_t)srow * (HIDDEN * 2) + scb, _d); \
    glds16(_s + (size_t)(srow + 64) * (HIDDEN * 2) + scb, _d + 8192); \
} while (0)
#define LDA2(cbase, mq) do { \
    _Pragma("unroll") for (int i = 0; i < 4; ++i) { \
        const char* _p = (cbase) + (size_t)((mq) * 128 + wr * 64 + i * 16 + l16) * 128; \
        a[i][0] = *(const bf16x8*)(_p + col0); \
        a[i][1] = *(const bf16x8*)(_p + col1); \
    } } while (0)
#define LDB2(cbase, nq) do { \
    _Pragma("unroll") for (int j = 0; j < 2; ++j) { \
        const char* _p = (cbase) + (size_t)((nq) * 128 + wc * 32 + j * 16 + l16) * 128; \
        b[j][0] = *(const bf16x8*)(_p + col0); \
        b[j][1] = *(const bf16x8*)(_p + col1); \
    } } while (0)
#define MMAQ2(mq, nq) do { \
    __builtin_amdgcn_s_setprio(1); \
    _Pragma("unroll") for (int i = 0; i < 4; ++i) \
    _Pragma("unroll") for (int j = 0; j < 2; ++j) { \
        acc[(mq)*4+i][(nq)*2+j] = __builtin_amdgcn_mfma_f32_16x16x32_bf16(a[i][0], b[j][0], acc[(mq)*4+i][(nq)*2+j], 0, 0, 0); \
        acc[(mq)*4+i][(nq)*2+j] = __builtin_amdgcn_mfma_f32_16x16x32_bf16(a[i][1], b[j][1], acc[(mq)*4+i][(nq)*2+j], 0, 0, 0); \
    } \
    __builtin_amdgcn_s_setprio(0); \
} while (0)

    STG_A2(0, 0, 0);
    STG_B2(0, 0, 0);
    STG_B2(0, 1, 0);
    STG_A2(0, 1, 0);
    VMC(4);
    BARR;

#pragma unroll 1
    for (int kt = 0; kt < NT2 - 1; ++kt) {
        const int c = kt & 1, o = c ^ 1;
        const char* Ac = AsB + c * 32768;
        const char* Bc = BsB + c * 32768;
        LDA2(Ac, 0); LDB2(Bc, 0);
        STG_A2(o, 0, kt + 1);
        VMC(4); BARR; LGK0;
        MMAQ2(0, 0); BARR;
        LDB2(Bc, 1);
        STG_B2(o, 0, kt + 1);
        VMC(4); BARR; LGK0;
        MMAQ2(0, 1); BARR;
        LDA2(Ac, 1);
        STG_B2(o, 1, kt + 1);
        BARR; LGK0;
        MMAQ2(1, 1); BARR;
        LDB2(Bc, 0);
        STG_A2(o, 1, kt + 1);
        VMC(4); BARR; LGK0;
        MMAQ2(1, 0); BARR;
    }
    {
        const int c = (NT2 - 1) & 1;
        const char* Ac = AsB + c * 32768;
        const char* Bc = BsB + c * 32768;
        LDA2(Ac, 0); LDB2(Bc, 0); VMC(2); BARR; LGK0; MMAQ2(0, 0); BARR;
        LDB2(Bc, 1);              VMC(0); BARR; LGK0; MMAQ2(0, 1); BARR;
        LDA2(Ac, 1);                      BARR; LGK0; MMAQ2(1, 1); BARR;
        LDB2(Bc, 0);                            LGK0; MMAQ2(1, 0);
    }

#pragma unroll
    for (int m = 0; m < 8; ++m) {
        const int mq = m >> 2, i = m & 3;
        const int row0 = bm * 256 + mq * 128 + wr * 64 + i * 16 + quad * 4;
#pragma unroll
        for (int n = 0; n < 4; ++n) {
            const int nq = n >> 1, j = n & 1;
            const int col = nq * 128 + wc * 32 + j * 16 + l16;   // bn == 0
            const float bias = b2[col];
#pragma unroll
            for (int r = 0; r < 4; ++r) {
                const int row = row0 + r;
                if (row < N_NODES) {
                    const size_t idx = (size_t)row * NODE_F + col;
                    out[idx] = acc[m][n][r] + bias + x[idx];
                }
            }
        }
    }
#undef STG_A2
#undef STG_B2
#undef LDA2
#undef LDB2
#undef MMAQ2
}

extern "C" void kernel_launch(void* const* d_in, const int* in_sizes, int n_in,
                              void* d_out, int out_size, void* d_ws, size_t ws_size,
                              hipStream_t stream) {
    const float* x         = (const float*)d_in[0];
    const float* edge_attr = (const float*)d_in[1];
    const float* u         = (const float*)d_in[2];
    const float* W1        = (const float*)d_in[3];
    const float* b1        = (const float*)d_in[4];
    const float* W2        = (const float*)d_in[5];
    const float* b2        = (const float*)d_in[6];
    const int*   edge_index= (const int*)d_in[7];
    const int*   batch     = (const int*)d_in[8];
    float*       out       = (float*)d_out;

    char* ws = (char*)d_ws;
    bf16* H    = (bf16*)(ws + H_OFF);
    bf16* hid  = (bf16*)(ws + HID_OFF);
    bf16* W1t  = (bf16*)(ws + W1T_OFF);
    bf16* W2t  = (bf16*)(ws + W2T_OFF);
    int*  deg  = (int*)(ws + DEG_OFF);
    int*  cur  = (int*)(ws + CUR_OFF);
    int*  start= (int*)(ws + START_OFF);
    int*  eids = (int*)(ws + EIDS_OFF);
    int*  bsum = (int*)(ws + BSUM_OFF);
    int*  boff = (int*)(ws + BOFF_OFF);

    const int* col = edge_index + N_EDGES;

    hipMemsetAsync(ws + DEG_OFF, 0, DEG_BYTES + CUR_BYTES, stream);
    hist_kernel<<<(N_EDGES + 255) / 256, 256, 0, stream>>>(col, deg);
    scan_phase1<<<SCAN_BLOCKS, 256, 0, stream>>>(deg, start, bsum);
    scan_phase2<<<1, 256, 0, stream>>>(bsum, boff, start);
    scan_phase3<<<SCAN_BLOCKS, 256, 0, stream>>>(start, boff);
    scatter_kernel<<<(N_EDGES + 255) / 256, 256, 0, stream>>>(col, start, cur, eids);
    build_h_kernel<<<M_PAD, 128, 0, stream>>>(x, edge_attr, u, batch, start, eids, H);
    transpose_kernel<<<dim3(HIDDEN / 32, KP / 32), 256, 0, stream>>>(W1, W1t, MLP_IN, HIDDEN, KP);
    transpose_kernel<<<dim3(NODE_F / 32, HIDDEN / 32), 256, 0, stream>>>(W2, W2t, HIDDEN, NODE_F, HIDDEN);
    gemm1_kernel<<<dim3(784), 512, 0, stream>>>(H, W1t, b1, hid);
    gemm2_kernel<<<dim3(196), 512, 0, stream>>>(hid, W2t, b2, x, out);
}

// Round 4
// 752.220 us; speedup vs baseline: 1.0612x; 1.0151x over previous
//
#include <hip/hip_runtime.h>
#include <stdint.h>

#define N_NODES 50000
#define N_EDGES 800000
#define EDGE_F  96
#define NODE_F  256
#define GLOB_F  64
#define HIDDEN  1024
#define MLP_IN  608           // 256 + 3*96 + 64 (valid K)
#define KP      640           // K padded to multiple of 64 for 8-phase GEMM1
#define M_PAD   50176         // 196 * 256
#define SCAN_BLOCKS 196       // 196*256 = 50176 >= 50000
#define NT1     10            // KP / 64
#define NT2     16            // HIDDEN / 64

typedef __bf16 bf16;
typedef __bf16 bf16x4 __attribute__((ext_vector_type(4)));
typedef __bf16 bf16x8 __attribute__((ext_vector_type(8)));
typedef float  f32x4  __attribute__((ext_vector_type(4)));

typedef __attribute__((address_space(1))) unsigned int gu32;
typedef __attribute__((address_space(3))) unsigned int lu32;

__device__ __forceinline__ void glds16(const void* g, void* l) {
    __builtin_amdgcn_global_load_lds((const gu32*)g, (lu32*)l, 16, 0, 0);
}

// ---------------- workspace layout (bytes) ----------------
static constexpr size_t H_OFF    = 0;
static constexpr size_t H_BYTES  = (size_t)M_PAD * KP * 2;
static constexpr size_t HID_OFF  = H_OFF + H_BYTES;
static constexpr size_t HID_BYTES= (size_t)M_PAD * HIDDEN * 2;
static constexpr size_t W1T_OFF  = HID_OFF + HID_BYTES;
static constexpr size_t W1T_BYTES= (size_t)HIDDEN * KP * 2;
static constexpr size_t W2T_OFF  = W1T_OFF + W1T_BYTES;
static constexpr size_t W2T_BYTES= (size_t)NODE_F * HIDDEN * 2;
static constexpr size_t DEG_OFF  = W2T_OFF + W2T_BYTES;
static constexpr size_t DEG_BYTES= 200192;
static constexpr size_t CUR_OFF  = DEG_OFF + DEG_BYTES;
static constexpr size_t CUR_BYTES= 200192;
static constexpr size_t START_OFF= CUR_OFF + CUR_BYTES;
static constexpr size_t START_BYTES = 200192;
static constexpr size_t EIDS_OFF = START_OFF + START_BYTES;
static constexpr size_t EIDS_BYTES = (size_t)N_EDGES * 4;
static constexpr size_t BSUM_OFF = EIDS_OFF + EIDS_BYTES;
static constexpr size_t BSUM_BYTES = 1024;
static constexpr size_t BOFF_OFF = BSUM_OFF + BSUM_BYTES;

// ---------------- CSR build ----------------
__global__ __launch_bounds__(256) void hist_kernel(const int* __restrict__ col,
                                                   int* __restrict__ deg) {
    int e = blockIdx.x * 256 + threadIdx.x;
    if (e < N_EDGES) atomicAdd(&deg[col[e]], 1);
}

__global__ __launch_bounds__(256) void scan_phase1(const int* __restrict__ deg,
                                                   int* __restrict__ start,
                                                   int* __restrict__ bsum) {
    __shared__ int sc[256];
    const int t = threadIdx.x, b = blockIdx.x;
    const int idx = b * 256 + t;
    int v = (idx < N_NODES) ? deg[idx] : 0;
    sc[t] = v;
    __syncthreads();
    for (int off = 1; off < 256; off <<= 1) {
        int add = (t >= off) ? sc[t - off] : 0;
        __syncthreads();
        sc[t] += add;
        __syncthreads();
    }
    if (idx < N_NODES) start[idx] = sc[t] - v;   // exclusive within block
    if (t == 255) bsum[b] = sc[255];
}

__global__ __launch_bounds__(256) void scan_phase2(int* __restrict__ bsum,
                                                   int* __restrict__ boff,
                                                   int* __restrict__ start) {
    __shared__ int sc[256];
    const int t = threadIdx.x;
    int v = (t < SCAN_BLOCKS) ? bsum[t] : 0;
    sc[t] = v;
    __syncthreads();
    for (int off = 1; off < 256; off <<= 1) {
        int add = (t >= off) ? sc[t - off] : 0;
        __syncthreads();
        sc[t] += add;
        __syncthreads();
    }
    if (t < SCAN_BLOCKS) boff[t] = sc[t] - v;    // exclusive block offsets
    if (t == 255) start[N_NODES] = sc[255];      // == N_EDGES (kept for safety)
}

// scan_phase3 eliminated: boff folded into consumers (scatter, build_h)

__global__ __launch_bounds__(256) void scatter_kernel(const int* __restrict__ col,
                                                      const int* __restrict__ start,
                                                      const int* __restrict__ boff,
                                                      int* __restrict__ cursor,
                                                      int* __restrict__ eids) {
    int e = blockIdx.x * 256 + threadIdx.x;
    if (e < N_EDGES) {
        int c = col[e];
        int p = start[c] + boff[c >> 8] + atomicAdd(&cursor[c], 1);
        eids[p] = e;
    }
}

// ---------------- build H = [x | sum | max | mean | u[batch] | 0-pad] bf16, stride KP ----
// float4 gather: lane t<96 handles float4-chunk (t%24) of edge-slot (t/24);
// 4 edges per round, unroll x2; cross-slot LDS tree reduction at the end.
#define BH_CHUNK 128
__global__ __launch_bounds__(128) void build_h_kernel(const float* __restrict__ x,
                                                      const float* __restrict__ edge_attr,
                                                      const float* __restrict__ u,
                                                      const int* __restrict__ batch,
                                                      const int* __restrict__ start,
                                                      const int* __restrict__ boff,
                                                      const int* __restrict__ eids,
                                                      bf16* __restrict__ H) {
    const int n = blockIdx.x;
    const int t = threadIdx.x;
    bf16* row = H + (size_t)n * KP;
    if (n >= N_NODES) {
        for (int c = t; c < KP; c += 128) row[c] = (bf16)0.0f;
        return;
    }
    if (t < 64) {
        float4 v = ((const float4*)(x + (size_t)n * NODE_F))[t];
        bf16x4 p;
        p.x = (bf16)v.x; p.y = (bf16)v.y; p.z = (bf16)v.z; p.w = (bf16)v.w;
        *(bf16x4*)(row + t * 4) = p;
    } else {
        int g = batch[n];
        row[544 + (t - 64)] = (bf16)u[g * GLOB_F + (t - 64)];
    }
    if (t >= 96) row[608 + (t - 96)] = (bf16)0.0f;   // K pad columns

    __shared__ int se[BH_CHUNK];
    __shared__ float4 red[96];
    const int s0 = start[n] + boff[n >> 8];
    const int s1 = (n == N_NODES - 1) ? N_EDGES
                                      : (start[n + 1] + boff[(n + 1) >> 8]);

    const int slot = t / 24;          // 0..3 (t<96); edge slot within round of 4
    const int f4   = t - slot * 24;   // 0..23; float4 chunk within the 96-f row

    float4 sm4; sm4.x = 0.0f; sm4.y = 0.0f; sm4.z = 0.0f; sm4.w = 0.0f;
    float4 mx4; mx4.x = -3.0e38f; mx4.y = -3.0e38f; mx4.z = -3.0e38f; mx4.w = -3.0e38f;

#define ACC4(v) do { \
    sm4.x += (v).x; sm4.y += (v).y; sm4.z += (v).z; sm4.w += (v).w; \
    mx4.x = fmaxf(mx4.x, (v).x); mx4.y = fmaxf(mx4.y, (v).y); \
    mx4.z = fmaxf(mx4.z, (v).z); mx4.w = fmaxf(mx4.w, (v).w); \
} while (0)

    for (int base = s0; base < s1; base += BH_CHUNK) {
        const int cnt = min(BH_CHUNK, s1 - base);
        __syncthreads();
        if (t < cnt) se[t] = eids[base + t];
        __syncthreads();
        if (t < 96) {
            int i = 0;
            for (; i + 8 <= cnt; i += 8) {
                float4 v0 = *(const float4*)(edge_attr + (size_t)se[i + slot]     * EDGE_F + f4 * 4);
                float4 v1 = *(const float4*)(edge_attr + (size_t)se[i + 4 + slot] * EDGE_F + f4 * 4);
                ACC4(v0);
                ACC4(v1);
            }
            for (; i + 4 <= cnt; i += 4) {
                float4 v0 = *(const float4*)(edge_attr + (size_t)se[i + slot] * EDGE_F + f4 * 4);
                ACC4(v0);
            }
            if (slot == 0) {
                for (int k = i; k < cnt; ++k) {
                    float4 v0 = *(const float4*)(edge_attr + (size_t)se[k] * EDGE_F + f4 * 4);
                    ACC4(v0);
                }
            }
        }
    }
#undef ACC4

    // cross-slot reduction: slots 0..3 -> lane group t<24
    __syncthreads();
    if (t < 96) red[t] = sm4;
    __syncthreads();
    float4 rs;
    if (t < 24) {
        float4 a0 = red[t], a1 = red[t + 24], a2 = red[t + 48], a3 = red[t + 72];
        rs.x = (a0.x + a1.x) + (a2.x + a3.x);
        rs.y = (a0.y + a1.y) + (a2.y + a3.y);
        rs.z = (a0.z + a1.z) + (a2.z + a3.z);
        rs.w = (a0.w + a1.w) + (a2.w + a3.w);
    }
    __syncthreads();
    if (t < 96) red[t] = mx4;
    __syncthreads();
    if (t < 24) {
        float4 a0 = red[t], a1 = red[t + 24], a2 = red[t + 48], a3 = red[t + 72];
        float4 rm;
        rm.x = fmaxf(fmaxf(a0.x, a1.x), fmaxf(a2.x, a3.x));
        rm.y = fmaxf(fmaxf(a0.y, a1.y), fmaxf(a2.y, a3.y));
        rm.z = fmaxf(fmaxf(a0.z, a1.z), fmaxf(a2.z, a3.z));
        rm.w = fmaxf(fmaxf(a0.w, a1.w), fmaxf(a2.w, a3.w));
        const int d = s1 - s0;
        if (d == 0) { rm.x = 0.0f; rm.y = 0.0f; rm.z = 0.0f; rm.w = 0.0f; }
        const float inv = 1.0f / fmaxf((float)d, 1.0f);
        bf16x4 ps, pm, pa;
        ps.x = (bf16)rs.x; ps.y = (bf16)rs.y; ps.z = (bf16)rs.z; ps.w = (bf16)rs.w;
        pm.x = (bf16)rm.x; pm.y = (bf16)rm.y; pm.z = (bf16)rm.z; pm.w = (bf16)rm.w;
        pa.x = (bf16)(rs.x * inv); pa.y = (bf16)(rs.y * inv);
        pa.z = (bf16)(rs.z * inv); pa.w = (bf16)(rs.w * inv);
        *(bf16x4*)(row + 256 + t * 4) = ps;
        *(bf16x4*)(row + 352 + t * 4) = pm;
        *(bf16x4*)(row + 448 + t * 4) = pa;
    }
}

// ---------------- transpose: W [K][N] f32 -> Wt [N][Kpad] bf16 (zero-fill k>=K) ----------
__global__ __launch_bounds__(256) void transpose_kernel(const float* __restrict__ W,
                                                        bf16* __restrict__ Wt,
                                                        int K, int N, int Kpad) {
    __shared__ float tile[32][33];
    const int tx = threadIdx.x & 31, ty = threadIdx.x >> 5;   // 32 x 8
    const int n0 = blockIdx.x * 32, k0 = blockIdx.y * 32;
    if (k0 < K) {
#pragma unroll
        for (int r = 0; r < 4; r++)
            tile[ty + 8 * r][tx] = W[(size_t)(k0 + ty + 8 * r) * N + (n0 + tx)];
    }
    __syncthreads();
#pragma unroll
    for (int r = 0; r < 4; r++)
        Wt[(size_t)(n0 + ty + 8 * r) * Kpad + (k0 + tx)] =
            (k0 < K) ? (bf16)tile[tx][ty + 8 * r] : (bf16)0.0f;
}

// ---------------- shared 8-phase GEMM schedule macros ----------------
#define VMC(n) asm volatile("s_waitcnt vmcnt(" #n ")" ::: "memory")
#define LGK0   asm volatile("s_waitcnt lgkmcnt(0)" ::: "memory")
#define BARR   __builtin_amdgcn_s_barrier()

// ---------------- GEMM1: hid = relu(H @ W1 + b1) --------------------------------
// 256x256 tile, BK=64, 512 threads (2Mx4N waves), 8-phase schedule:
// XOR-swizzled LDS (T2), counted vmcnt (T3/T4), setprio (T5), XCD swizzle (T1).
__global__ __launch_bounds__(512) void gemm1_kernel(const bf16* __restrict__ H,
                                                    const bf16* __restrict__ Wt,
                                                    const float* __restrict__ b1,
                                                    bf16* __restrict__ hid) {
    __shared__ __align__(16) bf16 As[2][256 * 64];
    __shared__ __align__(16) bf16 Bs[2][256 * 64];
    const int t = threadIdx.x;
    const int wave = t >> 6, lane = t & 63;
    const int quad = lane >> 4, l16 = lane & 15;
    const int wr = wave >> 2;          // 0..1 : M
    const int wc = wave & 3;           // 0..3 : N
    // XCD-chunked bijective swizzle: grid 784 = 8 * 98; bn fastest so the 4
    // bn-siblings of one bm (shared 320KB A-panel) land on the same XCD L2.
    const int orig = blockIdx.x;
    const int swz  = (orig & 7) * 98 + (orig >> 3);
    const int bm = swz >> 2, bn = swz & 3;

    f32x4 acc[8][4] = {};
    bf16x8 a[4][2], b[2][2];

    const int srow = t >> 3;                               // 0..63
    const int scb  = (((t & 7) ^ (srow & 7)) << 4);        // swizzled col-byte
    const char* Ag = (const char*)H  + (size_t)(bm * 256) * (KP * 2);
    const char* Bg = (const char*)Wt + (size_t)(bn * 256) * (KP * 2);
    char* AsB = (char*)&As[0][0];
    char* BsB = (char*)&Bs[0][0];

    const int swzl = (l16 & 7) << 4;
    const int col0 = (quad * 16) ^ swzl;                   // kh = 0
    const int col1 = (64 + quad * 16) ^ swzl;              // kh = 1

#define STG_A(buf, h, kt) do { \
    const char* _s = Ag + (size_t)((h) * 128) * (KP * 2) + (size_t)(kt) * 128; \
    char* _d = AsB + (buf) * 32768 + (h) * 16384 + t * 16; \
    glds16(_s + (size_t)srow * (KP * 2) + scb, _d); \
    glds16(_s + (size_t)(srow + 64) * (KP * 2) + scb, _d + 8192); \
} while (0)
#define STG_B(buf, h, kt) do { \
    const char* _s = Bg + (size_t)((h) * 128) * (KP * 2) + (size_t)(kt) * 128; \
    char* _d = BsB + (buf) * 32768 + (h) * 16384 + t * 16; \
    glds16(_s + (size_t)srow * (KP * 2) + scb, _d); \
    glds16(_s + (size_t)(srow + 64) * (KP * 2) + scb, _d + 8192); \
} while (0)
#define LDA(cbase, mq) do { \
    _Pragma("unroll") for (int i = 0; i < 4; ++i) { \
        const char* _p = (cbase) + (size_t)((mq) * 128 + wr * 64 + i * 16 + l16) * 128; \
        a[i][0] = *(const bf16x8*)(_p + col0); \
        a[i][1] = *(const bf16x8*)(_p + col1); \
    } } while (0)
#define LDB(cbase, nq) do { \
    _Pragma("unroll") for (int j = 0; j < 2; ++j) { \
        const char* _p = (cbase) + (size_t)((nq) * 128 + wc * 32 + j * 16 + l16) * 128; \
        b[j][0] = *(const bf16x8*)(_p + col0); \
        b[j][1] = *(const bf16x8*)(_p + col1); \
    } } while (0)
#define MMAQ(mq, nq) do { \
    __builtin_amdgcn_s_setprio(1); \
    _Pragma("unroll") for (int i = 0; i < 4; ++i) \
    _Pragma("unroll") for (int j = 0; j < 2; ++j) { \
        acc[(mq)*4+i][(nq)*2+j] = __builtin_amdgcn_mfma_f32_16x16x32_bf16(a[i][0], b[j][0], acc[(mq)*4+i][(nq)*2+j], 0, 0, 0); \
        acc[(mq)*4+i][(nq)*2+j] = __builtin_amdgcn_mfma_f32_16x16x32_bf16(a[i][1], b[j][1], acc[(mq)*4+i][(nq)*2+j], 0, 0, 0); \
    } \
    __builtin_amdgcn_s_setprio(0); \
} while (0)

    // prologue: stage tile 0 in consumption order A0,B0,B1,A1  (8 loads/thread)
    STG_A(0, 0, 0);
    STG_B(0, 0, 0);
    STG_B(0, 1, 0);
    STG_A(0, 1, 0);
    VMC(4);              // A0,B0 landed
    BARR;

    // steady FIFO ledger (2 loads/staging): enter with {B1,A1}=4 outstanding.
    // P1 +A0' -> 6, vmcnt(4) retires B1 | P2 +B0' -> 6, vmcnt(4) retires A1
    // P3 +B1' -> 6, no wait             | P4 +A1' -> 8, vmcnt(4) retires A0',B0'
#pragma unroll 1
    for (int kt = 0; kt < NT1 - 1; ++kt) {
        const int c = kt & 1, o = c ^ 1;
        const char* Ac = AsB + c * 32768;
        const char* Bc = BsB + c * 32768;
        LDA(Ac, 0); LDB(Bc, 0);
        STG_A(o, 0, kt + 1);
        VMC(4); BARR; LGK0;
        MMAQ(0, 0); BARR;
        LDB(Bc, 1);
        STG_B(o, 0, kt + 1);
        VMC(4); BARR; LGK0;
        MMAQ(0, 1); BARR;
        LDA(Ac, 1);
        STG_B(o, 1, kt + 1);
        BARR; LGK0;
        MMAQ(1, 1); BARR;
        LDB(Bc, 0);
        STG_A(o, 1, kt + 1);
        VMC(4); BARR; LGK0;
        MMAQ(1, 0); BARR;
    }
    {   // last tile: no staging; drain
        const int c = (NT1 - 1) & 1;
        const char* Ac = AsB + c * 32768;
        const char* Bc = BsB + c * 32768;
        LDA(Ac, 0); LDB(Bc, 0); VMC(2); BARR; LGK0; MMAQ(0, 0); BARR;
        LDB(Bc, 1);             VMC(0); BARR; LGK0; MMAQ(0, 1); BARR;
        LDA(Ac, 1);                     BARR; LGK0; MMAQ(1, 1); BARR;
        LDB(Bc, 0);                           LGK0; MMAQ(1, 0);
    }

#pragma unroll
    for (int m = 0; m < 8; ++m) {
        const int mq = m >> 2, i = m & 3;
        const int row0 = bm * 256 + mq * 128 + wr * 64 + i * 16 + quad * 4;
#pragma unroll
        for (int n = 0; n < 4; ++n) {
            const int nq = n >> 1, j = n & 1;
            const int col = bn * 256 + nq * 128 + wc * 32 + j * 16 + l16;
            const float bias = b1[col];
#pragma unroll
            for (int r = 0; r < 4; ++r) {
                float v = acc[m][n][r] + bias;
                v = fmaxf(v, 0.0f);
                hid[(size_t)(row0 + r) * HIDDEN + col] = (bf16)v;
            }
        }
    }
#undef STG_A
#undef STG_B
#undef LDA
#undef LDB
#undef MMAQ
}

// ---------------- GEMM2: out = hid @ W2 + b2 + x, fp32 out ----------------------
// Same 8-phase 256x256 structure; N=256 = exactly one tile (bn==0), NT2=16,
// grid = 196 blocks (one occupancy round at 1 block/CU).
__global__ __launch_bounds__(512) void gemm2_kernel(const bf16* __restrict__ Hd,
                                                    const bf16* __restrict__ Wt,
                                                    const float* __restrict__ b2,
                                                    const float* __restrict__ x,
                                                    float* __restrict__ out) {
    __shared__ __align__(16) bf16 As[2][256 * 64];
    __shared__ __align__(16) bf16 Bs[2][256 * 64];
    const int t = threadIdx.x;
    const int wave = t >> 6, lane = t & 63;
    const int quad = lane >> 4, l16 = lane & 15;
    const int wr = wave >> 2;          // 0..1 : M
    const int wc = wave & 3;           // 0..3 : N
    const int bm = blockIdx.x;

    f32x4 acc[8][4] = {};
    bf16x8 a[4][2], b[2][2];

    const int srow = t >> 3;                               // 0..63
    const int scb  = (((t & 7) ^ (srow & 7)) << 4);        // swizzled col-byte
    const char* Ag = (const char*)Hd + (size_t)(bm * 256) * (HIDDEN * 2);
    const char* Bg = (const char*)Wt;                      // 256 rows x HIDDEN
    char* AsB = (char*)&As[0][0];
    char* BsB = (char*)&Bs[0][0];

    const int swzl = (l16 & 7) << 4;
    const int col0 = (quad * 16) ^ swzl;                   // kh = 0
    const int col1 = (64 + quad * 16) ^ swzl;              // kh = 1

#define STG_A2(buf, h, kt) do { \
    const char* _s = Ag + (size_t)((h) * 128) * (HIDDEN * 2) + (size_t)(kt) * 128; \
    char* _d = AsB + (buf) * 32768 + (h) * 16384 + t * 16; \
    glds16(_s + (size_t)srow * (HIDDEN * 2) + scb, _d); \
    glds16(_s + (size_t)(srow + 64) * (HIDDEN * 2) + scb, _d + 8192); \
} while (0)
#define STG_B2(buf, h, kt) do { \
    const char* _s = Bg + (size_t)((h) * 128) * (HIDDEN * 2) + (size_t)(kt) * 128; \
    char* _d = BsB + (buf) * 32768 + (h) * 16384 + t * 16; \
    glds16(_s + (size_t)srow * (HIDDEN * 2) + scb, _d); \
    glds16(_s + (size_t)(srow + 64) * (HIDDEN * 2) + scb, _d + 8192); \
} while (0)
#define LDA2(cbase, mq) do { \
    _Pragma("unroll") for (int i = 0; i < 4; ++i) { \
        const char* _p = (cbase) + (size_t)((mq) * 128 + wr * 64 + i * 16 + l16) * 128; \
        a[i][0] = *(const bf16x8*)(_p + col0); \
        a[i][1] = *(const bf16x8*)(_p + col1); \
    } } while (0)
#define LDB2(cbase, nq) do { \
    _Pragma("unroll") for (int j = 0; j < 2; ++j) { \
        const char* _p = (cbase) + (size_t)((nq) * 128 + wc * 32 + j * 16 + l16) * 128; \
        b[j][0] = *(const bf16x8*)(_p + col0); \
        b[j][1] = *(const bf16x8*)(_p + col1); \
    } } while (0)
#define MMAQ2(mq, nq) do { \
    __builtin_amdgcn_s_setprio(1); \
    _Pragma("unroll") for (int i = 0; i < 4; ++i) \
    _Pragma("unroll") for (int j = 0; j < 2; ++j) { \
        acc[(mq)*4+i][(nq)*2+j] = __builtin_amdgcn_mfma_f32_16x16x32_bf16(a[i][0], b[j][0], acc[(mq)*4+i][(nq)*2+j], 0, 0, 0); \
        acc[(mq)*4+i][(nq)*2+j] = __builtin_amdgcn_mfma_f32_16x16x32_bf16(a[i][1], b[j][1], acc[(mq)*4+i][(nq)*2+j], 0, 0, 0); \
    } \
    __builtin_amdgcn_s_setprio(0); \
} while (0)

    STG_A2(0, 0, 0);
    STG_B2(0, 0, 0);
    STG_B2(0, 1, 0);
    STG_A2(0, 1, 0);
    VMC(4);
    BARR;

#pragma unroll 1
    for (int kt = 0; kt < NT2 - 1; ++kt) {
        const int c = kt & 1, o = c ^ 1;
        const char* Ac = AsB + c * 32768;
        const char* Bc = BsB + c * 32768;
        LDA2(Ac, 0); LDB2(Bc, 0);
        STG_A2(o, 0, kt + 1);
        VMC(4); BARR; LGK0;
        MMAQ2(0, 0); BARR;
        LDB2(Bc, 1);
        STG_B2(o, 0, kt + 1);
        VMC(4); BARR; LGK0;
        MMAQ2(0, 1); BARR;
        LDA2(Ac, 1);
        STG_B2(o, 1, kt + 1);
        BARR; LGK0;
        MMAQ2(1, 1); BARR;
        LDB2(Bc, 0);
        STG_A2(o, 1, kt + 1);
        VMC(4); BARR; LGK0;
        MMAQ2(1, 0); BARR;
    }
    {
        const int c = (NT2 - 1) & 1;
        const char* Ac = AsB + c * 32768;
        const char* Bc = BsB + c * 32768;
        LDA2(Ac, 0); LDB2(Bc, 0); VMC(2); BARR; LGK0; MMAQ2(0, 0); BARR;
        LDB2(Bc, 1);              VMC(0); BARR; LGK0; MMAQ2(0, 1); BARR;
        LDA2(Ac, 1);                      BARR; LGK0; MMAQ2(1, 1); BARR;
        LDB2(Bc, 0);                            LGK0; MMAQ2(1, 0);
    }

#pragma unroll
    for (int m = 0; m < 8; ++m) {
        const int mq = m >> 2, i = m & 3;
        const int row0 = bm * 256 + mq * 128 + wr * 64 + i * 16 + quad * 4;
#pragma unroll
        for (int n = 0; n < 4; ++n) {
            const int nq = n >> 1, j = n & 1;
            const int col = nq * 128 + wc * 32 + j * 16 + l16;   // bn == 0
            const float bias = b2[col];
#pragma unroll
            for (int r = 0; r < 4; ++r) {
                const int row = row0 + r;
                if (row < N_NODES) {
                    const size_t idx = (size_t)row * NODE_F + col;
                    out[idx] = acc[m][n][r] + bias + x[idx];
                }
            }
        }
    }
#undef STG_A2
#undef STG_B2
#undef LDA2
#undef LDB2
#undef MMAQ2
}

extern "C" void kernel_launch(void* const* d_in, const int* in_sizes, int n_in,
                              void* d_out, int out_size, void* d_ws, size_t ws_size,
                              hipStream_t stream) {
    const float* x         = (const float*)d_in[0];
    const float* edge_attr = (const float*)d_in[1];
    const float* u         = (const float*)d_in[2];
    const float* W1        = (const float*)d_in[3];
    const float* b1        = (const float*)d_in[4];
    const float* W2        = (const float*)d_in[5];
    const float* b2        = (const float*)d_in[6];
    const int*   edge_index= (const int*)d_in[7];
    const int*   batch     = (const int*)d_in[8];
    float*       out       = (float*)d_out;

    char* ws = (char*)d_ws;
    bf16* H    = (bf16*)(ws + H_OFF);
    bf16* hid  = (bf16*)(ws + HID_OFF);
    bf16* W1t  = (bf16*)(ws + W1T_OFF);
    bf16* W2t  = (bf16*)(ws + W2T_OFF);
    int*  deg  = (int*)(ws + DEG_OFF);
    int*  cur  = (int*)(ws + CUR_OFF);
    int*  start= (int*)(ws + START_OFF);
    int*  eids = (int*)(ws + EIDS_OFF);
    int*  bsum = (int*)(ws + BSUM_OFF);
    int*  boff = (int*)(ws + BOFF_OFF);

    const int* col = edge_index + N_EDGES;

    hipMemsetAsync(ws + DEG_OFF, 0, DEG_BYTES + CUR_BYTES, stream);
    hist_kernel<<<(N_EDGES + 255) / 256, 256, 0, stream>>>(col, deg);
    scan_phase1<<<SCAN_BLOCKS, 256, 0, stream>>>(deg, start, bsum);
    scan_phase2<<<1, 256, 0, stream>>>(bsum, boff, start);
    scatter_kernel<<<(N_EDGES + 255) / 256, 256, 0, stream>>>(col, start, boff, cur, eids);
    build_h_kernel<<<M_PAD, 128, 0, stream>>>(x, edge_attr, u, batch, start, boff, eids, H);
    transpose_kernel<<<dim3(HIDDEN / 32, KP / 32), 256, 0, stream>>>(W1, W1t, MLP_IN, HIDDEN, KP);
    transpose_kernel<<<dim3(NODE_F / 32, HIDDEN / 32), 256, 0, stream>>>(W2, W2t, HIDDEN, NODE_F, HIDDEN);
    gemm1_kernel<<<dim3(784), 512, 0, stream>>>(H, W1t, b1, hid);
    gemm2_kernel<<<dim3(196), 512, 0, stream>>>(hid, W2t, b2, x, out);
}

// Round 5
// 733.240 us; speedup vs baseline: 1.0886x; 1.0259x over previous
//
#include <hip/hip_runtime.h>
#include <stdint.h>

#define N_NODES 50000
#define N_EDGES 800000
#define EDGE_F  96
#define NODE_F  256
#define GLOB_F  64
#define HIDDEN  1024
#define MLP_IN  608           // 256 + 3*96 + 64 (valid K)
#define KP      640           // K padded to multiple of 64 for 8-phase GEMM1
#define M_PAD   50176         // 196 * 256
#define SCAN_BLOCKS 196       // 196*256 = 50176 >= 50000
#define NT1     10            // KP / 64
#define NT2     16            // HIDDEN / 64

typedef __bf16 bf16;
typedef __bf16 bf16x4 __attribute__((ext_vector_type(4)));
typedef __bf16 bf16x8 __attribute__((ext_vector_type(8)));
typedef float  f32x4  __attribute__((ext_vector_type(4)));

typedef __attribute__((address_space(1))) unsigned int gu32;
typedef __attribute__((address_space(3))) unsigned int lu32;

__device__ __forceinline__ void glds16(const void* g, void* l) {
    __builtin_amdgcn_global_load_lds((const gu32*)g, (lu32*)l, 16, 0, 0);
}

// ---------------- workspace layout (bytes) ----------------
static constexpr size_t H_OFF    = 0;
static constexpr size_t H_BYTES  = (size_t)M_PAD * KP * 2;
static constexpr size_t HID_OFF  = H_OFF + H_BYTES;
static constexpr size_t HID_BYTES= (size_t)M_PAD * HIDDEN * 2;
static constexpr size_t W1T_OFF  = HID_OFF + HID_BYTES;
static constexpr size_t W1T_BYTES= (size_t)HIDDEN * KP * 2;
static constexpr size_t W2T_OFF  = W1T_OFF + W1T_BYTES;
static constexpr size_t W2T_BYTES= (size_t)NODE_F * HIDDEN * 2;
static constexpr size_t DEG_OFF  = W2T_OFF + W2T_BYTES;
static constexpr size_t DEG_BYTES= 200192;
static constexpr size_t START_OFF= DEG_OFF + DEG_BYTES;
static constexpr size_t START_BYTES = 200192;
static constexpr size_t EIDS_OFF = START_OFF + START_BYTES;
static constexpr size_t EIDS_BYTES = (size_t)N_EDGES * 4;
static constexpr size_t RANK_OFF = EIDS_OFF + EIDS_BYTES;
static constexpr size_t RANK_BYTES = (size_t)N_EDGES * 4;
static constexpr size_t BSUM_OFF = RANK_OFF + RANK_BYTES;
static constexpr size_t BSUM_BYTES = 1024;
static constexpr size_t BOFF_OFF = BSUM_OFF + BSUM_BYTES;

// ---------------- CSR build (rank-based, single atomic pass) ----------------
__global__ __launch_bounds__(256) void hist_rank_kernel(const int* __restrict__ col,
                                                        int* __restrict__ deg,
                                                        int* __restrict__ rank) {
    int e = blockIdx.x * 256 + threadIdx.x;
    if (e < N_EDGES) rank[e] = atomicAdd(&deg[col[e]], 1);
}

__global__ __launch_bounds__(256) void scan_phase1(const int* __restrict__ deg,
                                                   int* __restrict__ start,
                                                   int* __restrict__ bsum) {
    __shared__ int sc[256];
    const int t = threadIdx.x, b = blockIdx.x;
    const int idx = b * 256 + t;
    int v = (idx < N_NODES) ? deg[idx] : 0;
    sc[t] = v;
    __syncthreads();
    for (int off = 1; off < 256; off <<= 1) {
        int add = (t >= off) ? sc[t - off] : 0;
        __syncthreads();
        sc[t] += add;
        __syncthreads();
    }
    if (idx < N_NODES) start[idx] = sc[t] - v;   // exclusive within block
    if (t == 255) bsum[b] = sc[255];
}

__global__ __launch_bounds__(256) void scan_phase2(int* __restrict__ bsum,
                                                   int* __restrict__ boff,
                                                   int* __restrict__ start) {
    __shared__ int sc[256];
    const int t = threadIdx.x;
    int v = (t < SCAN_BLOCKS) ? bsum[t] : 0;
    sc[t] = v;
    __syncthreads();
    for (int off = 1; off < 256; off <<= 1) {
        int add = (t >= off) ? sc[t - off] : 0;
        __syncthreads();
        sc[t] += add;
        __syncthreads();
    }
    if (t < SCAN_BLOCKS) boff[t] = sc[t] - v;    // exclusive block offsets
    if (t == 255) start[N_NODES] = sc[255];      // == N_EDGES
}

// atomic-free placement: slot = global start + per-edge rank
__global__ __launch_bounds__(256) void place_kernel(const int* __restrict__ col,
                                                    const int* __restrict__ start,
                                                    const int* __restrict__ boff,
                                                    const int* __restrict__ rank,
                                                    int* __restrict__ eids) {
    int e = blockIdx.x * 256 + threadIdx.x;
    if (e < N_EDGES) {
        int c = col[e];
        eids[start[c] + boff[c >> 8] + rank[e]] = e;
    }
}

// ---------------- build H = [x | sum | max | mean | u[batch] | 0-pad] bf16, stride KP ----
// float4 gather: lane t<96 handles float4-chunk (t%24) of edge-slot (t/24);
// unroll x4 -> 4 independent 16B loads in flight per lane (latency pipeline).
#define BH_CHUNK 128
__global__ __launch_bounds__(128) void build_h_kernel(const float* __restrict__ x,
                                                      const float* __restrict__ edge_attr,
                                                      const float* __restrict__ u,
                                                      const int* __restrict__ batch,
                                                      const int* __restrict__ start,
                                                      const int* __restrict__ boff,
                                                      const int* __restrict__ eids,
                                                      bf16* __restrict__ H) {
    const int n = blockIdx.x;
    const int t = threadIdx.x;
    bf16* row = H + (size_t)n * KP;
    if (n >= N_NODES) {
        for (int c = t; c < KP; c += 128) row[c] = (bf16)0.0f;
        return;
    }
    if (t < 64) {
        float4 v = ((const float4*)(x + (size_t)n * NODE_F))[t];
        bf16x4 p;
        p.x = (bf16)v.x; p.y = (bf16)v.y; p.z = (bf16)v.z; p.w = (bf16)v.w;
        *(bf16x4*)(row + t * 4) = p;
    } else {
        int g = batch[n];
        row[544 + (t - 64)] = (bf16)u[g * GLOB_F + (t - 64)];
    }
    if (t >= 96) row[608 + (t - 96)] = (bf16)0.0f;   // K pad columns

    __shared__ int se[BH_CHUNK];
    __shared__ float4 red[96];
    const int s0 = start[n] + boff[n >> 8];
    const int s1 = (n == N_NODES - 1) ? N_EDGES
                                      : (start[n + 1] + boff[(n + 1) >> 8]);

    const int slot = t / 24;          // 0..3 (t<96); edge slot within round of 4
    const int f4   = t - slot * 24;   // 0..23; float4 chunk within the 96-f row

    float4 sm4; sm4.x = 0.0f; sm4.y = 0.0f; sm4.z = 0.0f; sm4.w = 0.0f;
    float4 mx4; mx4.x = -3.0e38f; mx4.y = -3.0e38f; mx4.z = -3.0e38f; mx4.w = -3.0e38f;

#define ACC4(v) do { \
    sm4.x += (v).x; sm4.y += (v).y; sm4.z += (v).z; sm4.w += (v).w; \
    mx4.x = fmaxf(mx4.x, (v).x); mx4.y = fmaxf(mx4.y, (v).y); \
    mx4.z = fmaxf(mx4.z, (v).z); mx4.w = fmaxf(mx4.w, (v).w); \
} while (0)

    for (int base = s0; base < s1; base += BH_CHUNK) {
        const int cnt = min(BH_CHUNK, s1 - base);
        __syncthreads();
        if (t < cnt) se[t] = eids[base + t];
        __syncthreads();
        if (t < 96) {
            int i = 0;
            for (; i + 16 <= cnt; i += 16) {
                float4 v0 = *(const float4*)(edge_attr + (size_t)se[i + slot]      * EDGE_F + f4 * 4);
                float4 v1 = *(const float4*)(edge_attr + (size_t)se[i + 4 + slot]  * EDGE_F + f4 * 4);
                float4 v2 = *(const float4*)(edge_attr + (size_t)se[i + 8 + slot]  * EDGE_F + f4 * 4);
                float4 v3 = *(const float4*)(edge_attr + (size_t)se[i + 12 + slot] * EDGE_F + f4 * 4);
                ACC4(v0); ACC4(v1); ACC4(v2); ACC4(v3);
            }
            for (; i + 4 <= cnt; i += 4) {
                float4 v0 = *(const float4*)(edge_attr + (size_t)se[i + slot] * EDGE_F + f4 * 4);
                ACC4(v0);
            }
            if (slot == 0) {
                for (int k = i; k < cnt; ++k) {
                    float4 v0 = *(const float4*)(edge_attr + (size_t)se[k] * EDGE_F + f4 * 4);
                    ACC4(v0);
                }
            }
        }
    }
#undef ACC4

    // cross-slot reduction: slots 0..3 -> lane group t<24
    __syncthreads();
    if (t < 96) red[t] = sm4;
    __syncthreads();
    float4 rs;
    if (t < 24) {
        float4 a0 = red[t], a1 = red[t + 24], a2 = red[t + 48], a3 = red[t + 72];
        rs.x = (a0.x + a1.x) + (a2.x + a3.x);
        rs.y = (a0.y + a1.y) + (a2.y + a3.y);
        rs.z = (a0.z + a1.z) + (a2.z + a3.z);
        rs.w = (a0.w + a1.w) + (a2.w + a3.w);
    }
    __syncthreads();
    if (t < 96) red[t] = mx4;
    __syncthreads();
    if (t < 24) {
        float4 a0 = red[t], a1 = red[t + 24], a2 = red[t + 48], a3 = red[t + 72];
        float4 rm;
        rm.x = fmaxf(fmaxf(a0.x, a1.x), fmaxf(a2.x, a3.x));
        rm.y = fmaxf(fmaxf(a0.y, a1.y), fmaxf(a2.y, a3.y));
        rm.z = fmaxf(fmaxf(a0.z, a1.z), fmaxf(a2.z, a3.z));
        rm.w = fmaxf(fmaxf(a0.w, a1.w), fmaxf(a2.w, a3.w));
        const int d = s1 - s0;
        if (d == 0) { rm.x = 0.0f; rm.y = 0.0f; rm.z = 0.0f; rm.w = 0.0f; }
        const float inv = 1.0f / fmaxf((float)d, 1.0f);
        bf16x4 ps, pm, pa;
        ps.x = (bf16)rs.x; ps.y = (bf16)rs.y; ps.z = (bf16)rs.z; ps.w = (bf16)rs.w;
        pm.x = (bf16)rm.x; pm.y = (bf16)rm.y; pm.z = (bf16)rm.z; pm.w = (bf16)rm.w;
        pa.x = (bf16)(rs.x * inv); pa.y = (bf16)(rs.y * inv);
        pa.z = (bf16)(rs.z * inv); pa.w = (bf16)(rs.w * inv);
        *(bf16x4*)(row + 256 + t * 4) = ps;
        *(bf16x4*)(row + 352 + t * 4) = pm;
        *(bf16x4*)(row + 448 + t * 4) = pa;
    }
}

// ---------------- merged transpose: W1 and W2 in one launch ----------------
// tiles 0..639: W1 [608][1024] -> W1t [1024][640]; tiles 640..895: W2 [1024][256] -> W2t [256][1024]
__global__ __launch_bounds__(256) void transpose2_kernel(const float* __restrict__ W1,
                                                         bf16* __restrict__ W1t,
                                                         const float* __restrict__ W2,
                                                         bf16* __restrict__ W2t) {
    __shared__ float tile[32][33];
    const int tx = threadIdx.x & 31, ty = threadIdx.x >> 5;   // 32 x 8
    int bid = blockIdx.x;
    const float* W; bf16* Wt; int K, N, Kpad, n0, k0;
    if (bid < 640) {
        W = W1; Wt = (bf16*)W1t; K = MLP_IN; N = HIDDEN; Kpad = KP;
        n0 = (bid & 31) * 32; k0 = (bid >> 5) * 32;
    } else {
        bid -= 640;
        W = W2; Wt = (bf16*)W2t; K = HIDDEN; N = NODE_F; Kpad = HIDDEN;
        n0 = (bid & 7) * 32; k0 = (bid >> 3) * 32;
    }
    if (k0 < K) {
#pragma unroll
        for (int r = 0; r < 4; r++)
            tile[ty + 8 * r][tx] = W[(size_t)(k0 + ty + 8 * r) * N + (n0 + tx)];
    }
    __syncthreads();
#pragma unroll
    for (int r = 0; r < 4; r++)
        Wt[(size_t)(n0 + ty + 8 * r) * Kpad + (k0 + tx)] =
            (k0 < K) ? (bf16)tile[tx][ty + 8 * r] : (bf16)0.0f;
}

// ---------------- shared 8-phase GEMM schedule macros ----------------
#define VMC(n) asm volatile("s_waitcnt vmcnt(" #n ")" ::: "memory")
#define LGK0   asm volatile("s_waitcnt lgkmcnt(0)" ::: "memory")
#define BARR   __builtin_amdgcn_s_barrier()

// ---------------- GEMM1: hid = relu(H @ W1 + b1) --------------------------------
// 256x256 tile, BK=64, 512 threads (2Mx4N waves), 8-phase schedule:
// XOR-swizzled LDS (T2), counted vmcnt (T3/T4), setprio (T5), XCD swizzle (T1).
__global__ __launch_bounds__(512) void gemm1_kernel(const bf16* __restrict__ H,
                                                    const bf16* __restrict__ Wt,
                                                    const float* __restrict__ b1,
                                                    bf16* __restrict__ hid) {
    __shared__ __align__(16) bf16 As[2][256 * 64];
    __shared__ __align__(16) bf16 Bs[2][256 * 64];
    const int t = threadIdx.x;
    const int wave = t >> 6, lane = t & 63;
    const int quad = lane >> 4, l16 = lane & 15;
    const int wr = wave >> 2;          // 0..1 : M
    const int wc = wave & 3;           // 0..3 : N
    // XCD-chunked bijective swizzle: grid 784 = 8 * 98; bn fastest so the 4
    // bn-siblings of one bm (shared 320KB A-panel) land on the same XCD L2.
    const int orig = blockIdx.x;
    const int swz  = (orig & 7) * 98 + (orig >> 3);
    const int bm = swz >> 2, bn = swz & 3;

    f32x4 acc[8][4] = {};
    bf16x8 a[4][2], b[2][2];

    const int srow = t >> 3;                               // 0..63
    const int scb  = (((t & 7) ^ (srow & 7)) << 4);        // swizzled col-byte
    const char* Ag = (const char*)H  + (size_t)(bm * 256) * (KP * 2);
    const char* Bg = (const char*)Wt + (size_t)(bn * 256) * (KP * 2);
    char* AsB = (char*)&As[0][0];
    char* BsB = (char*)&Bs[0][0];

    const int swzl = (l16 & 7) << 4;
    const int col0 = (quad * 16) ^ swzl;                   // kh = 0
    const int col1 = (64 + quad * 16) ^ swzl;              // kh = 1

#define STG_A(buf, h, kt) do { \
    const char* _s = Ag + (size_t)((h) * 128) * (KP * 2) + (size_t)(kt) * 128; \
    char* _d = AsB + (buf) * 32768 + (h) * 16384 + t * 16; \
    glds16(_s + (size_t)srow * (KP * 2) + scb, _d); \
    glds16(_s + (size_t)(srow + 64) * (KP * 2) + scb, _d + 8192); \
} while (0)
#define STG_B(buf, h, kt) do { \
    const char* _s = Bg + (size_t)((h) * 128) * (KP * 2) + (size_t)(kt) * 128; \
    char* _d = BsB + (buf) * 32768 + (h) * 16384 + t * 16; \
    glds16(_s + (size_t)srow * (KP * 2) + scb, _d); \
    glds16(_s + (size_t)(srow + 64) * (KP * 2) + scb, _d + 8192); \
} while (0)
#define LDA(cbase, mq) do { \
    _Pragma("unroll") for (int i = 0; i < 4; ++i) { \
        const char* _p = (cbase) + (size_t)((mq) * 128 + wr * 64 + i * 16 + l16) * 128; \
        a[i][0] = *(const bf16x8*)(_p + col0); \
        a[i][1] = *(const bf16x8*)(_p + col1); \
    } } while (0)
#define LDB(cbase, nq) do { \
    _Pragma("unroll") for (int j = 0; j < 2; ++j) { \
        const char* _p = (cbase) + (size_t)((nq) * 128 + wc * 32 + j * 16 + l16) * 128; \
        b[j][0] = *(const bf16x8*)(_p + col0); \
        b[j][1] = *(const bf16x8*)(_p + col1); \
    } } while (0)
#define MMAQ(mq, nq) do { \
    __builtin_amdgcn_s_setprio(1); \
    _Pragma("unroll") for (int i = 0; i < 4; ++i) \
    _Pragma("unroll") for (int j = 0; j < 2; ++j) { \
        acc[(mq)*4+i][(nq)*2+j] = __builtin_amdgcn_mfma_f32_16x16x32_bf16(a[i][0], b[j][0], acc[(mq)*4+i][(nq)*2+j], 0, 0, 0); \
        acc[(mq)*4+i][(nq)*2+j] = __builtin_amdgcn_mfma_f32_16x16x32_bf16(a[i][1], b[j][1], acc[(mq)*4+i][(nq)*2+j], 0, 0, 0); \
    } \
    __builtin_amdgcn_s_setprio(0); \
} while (0)

    // prologue: stage tile 0 in consumption order A0,B0,B1,A1  (8 loads/thread)
    STG_A(0, 0, 0);
    STG_B(0, 0, 0);
    STG_B(0, 1, 0);
    STG_A(0, 1, 0);
    VMC(4);              // A0,B0 landed
    BARR;

    // steady FIFO ledger (2 loads/staging): enter with {B1,A1}=4 outstanding.
    // P1 +A0' -> 6, vmcnt(4) retires B1 | P2 +B0' -> 6, vmcnt(4) retires A1
    // P3 +B1' -> 6, no wait             | P4 +A1' -> 8, vmcnt(4) retires A0',B0'
#pragma unroll 1
    for (int kt = 0; kt < NT1 - 1; ++kt) {
        const int c = kt & 1, o = c ^ 1;
        const char* Ac = AsB + c * 32768;
        const char* Bc = BsB + c * 32768;
        LDA(Ac, 0); LDB(Bc, 0);
        STG_A(o, 0, kt + 1);
        VMC(4); BARR; LGK0;
        MMAQ(0, 0); BARR;
        LDB(Bc, 1);
        STG_B(o, 0, kt + 1);
        VMC(4); BARR; LGK0;
        MMAQ(0, 1); BARR;
        LDA(Ac, 1);
        STG_B(o, 1, kt + 1);
        BARR; LGK0;
        MMAQ(1, 1); BARR;
        LDB(Bc, 0);
        STG_A(o, 1, kt + 1);
        VMC(4); BARR; LGK0;
        MMAQ(1, 0); BARR;
    }
    {   // last tile: no staging; drain
        const int c = (NT1 - 1) & 1;
        const char* Ac = AsB + c * 32768;
        const char* Bc = BsB + c * 32768;
        LDA(Ac, 0); LDB(Bc, 0); VMC(2); BARR; LGK0; MMAQ(0, 0); BARR;
        LDB(Bc, 1);             VMC(0); BARR; LGK0; MMAQ(0, 1); BARR;
        LDA(Ac, 1);                     BARR; LGK0; MMAQ(1, 1); BARR;
        LDB(Bc, 0);                           LGK0; MMAQ(1, 0);
    }

#pragma unroll
    for (int m = 0; m < 8; ++m) {
        const int mq = m >> 2, i = m & 3;
        const int row0 = bm * 256 + mq * 128 + wr * 64 + i * 16 + quad * 4;
#pragma unroll
        for (int n = 0; n < 4; ++n) {
            const int nq = n >> 1, j = n & 1;
            const int col = bn * 256 + nq * 128 + wc * 32 + j * 16 + l16;
            const float bias = b1[col];
#pragma unroll
            for (int r = 0; r < 4; ++r) {
                float v = acc[m][n][r] + bias;
                v = fmaxf(v, 0.0f);
                hid[(size_t)(row0 + r) * HIDDEN + col] = (bf16)v;
            }
        }
    }
#undef STG_A
#undef STG_B
#undef LDA
#undef LDB
#undef MMAQ
}

// ---------------- GEMM2: out = hid @ W2 + b2 + x, fp32 out ----------------------
// Same 8-phase 256x256 structure; N=256 = exactly one tile (bn==0), NT2=16,
// grid = 196 blocks (one occupancy round at 1 block/CU).
__global__ __launch_bounds__(512) void gemm2_kernel(const bf16* __restrict__ Hd,
                                                    const bf16* __restrict__ Wt,
                                                    const float* __restrict__ b2,
                                                    const float* __restrict__ x,
                                                    float* __restrict__ out) {
    __shared__ __align__(16) bf16 As[2][256 * 64];
    __shared__ __align__(16) bf16 Bs[2][256 * 64];
    const int t = threadIdx.x;
    const int wave = t >> 6, lane = t & 63;
    const int quad = lane >> 4, l16 = lane & 15;
    const int wr = wave >> 2;          // 0..1 : M
    const int wc = wave & 3;           // 0..3 : N
    const int bm = blockIdx.x;

    f32x4 acc[8][4] = {};
    bf16x8 a[4][2], b[2][2];

    const int srow = t >> 3;                               // 0..63
    const int scb  = (((t & 7) ^ (srow & 7)) << 4);        // swizzled col-byte
    const char* Ag = (const char*)Hd + (size_t)(bm * 256) * (HIDDEN * 2);
    const char* Bg = (const char*)Wt;                      // 256 rows x HIDDEN
    char* AsB = (char*)&As[0][0];
    char* BsB = (char*)&Bs[0][0];

    const int swzl = (l16 & 7) << 4;
    const int col0 = (quad * 16) ^ swzl;                   // kh = 0
    const int col1 = (64 + quad * 16) ^ swzl;              // kh = 1

#define STG_A2(buf, h, kt) do { \
    const char* _s = Ag + (size_t)((h) * 128) * (HIDDEN * 2) + (size_t)(kt) * 128; \
    char* _d = AsB + (buf) * 32768 + (h) * 16384 + t * 16; \
    glds16(_s + (size_t)srow * (HIDDEN * 2) + scb, _d); \
    glds16(_s + (size_t)(srow + 64) * (HIDDEN * 2) + scb, _d + 8192); \
} while (0)
#define STG_B2(buf, h, kt) do { \
    const char* _s = Bg + (size_t)((h) * 128) * (HIDDEN * 2) + (size_t)(kt) * 128; \
    char* _d = BsB + (buf) * 32768 + (h) * 16384 + t * 16; \
    glds16(_s + (size_t)srow * (HIDDEN * 2) + scb, _d); \
    glds16(_s + (size_t)(srow + 64) * (HIDDEN * 2) + scb, _d + 8192); \
} while (0)
#define LDA2(cbase, mq) do { \
    _Pragma("unroll") for (int i = 0; i < 4; ++i) { \
        const char* _p = (cbase) + (size_t)((mq) * 128 + wr * 64 + i * 16 + l16) * 128; \
        a[i][0] = *(const bf16x8*)(_p + col0); \
        a[i][1] = *(const bf16x8*)(_p + col1); \
    } } while (0)
#define LDB2(cbase, nq) do { \
    _Pragma("unroll") for (int j = 0; j < 2; ++j) { \
        const char* _p = (cbase) + (size_t)((nq) * 128 + wc * 32 + j * 16 + l16) * 128; \
        b[j][0] = *(const bf16x8*)(_p + col0); \
        b[j][1] = *(const bf16x8*)(_p + col1); \
    } } while (0)
#define MMAQ2(mq, nq) do { \
    __builtin_amdgcn_s_setprio(1); \
    _Pragma("unroll") for (int i = 0; i < 4; ++i) \
    _Pragma("unroll") for (int j = 0; j < 2; ++j) { \
        acc[(mq)*4+i][(nq)*2+j] = __builtin_amdgcn_mfma_f32_16x16x32_bf16(a[i][0], b[j][0], acc[(mq)*4+i][(nq)*2+j], 0, 0, 0); \
        acc[(mq)*4+i][(nq)*2+j] = __builtin_amdgcn_mfma_f32_16x16x32_bf16(a[i][1], b[j][1], acc[(mq)*4+i][(nq)*2+j], 0, 0, 0); \
    } \
    __builtin_amdgcn_s_setprio(0); \
} while (0)

    STG_A2(0, 0, 0);
    STG_B2(0, 0, 0);
    STG_B2(0, 1, 0);
    STG_A2(0, 1, 0);
    VMC(4);
    BARR;

#pragma unroll 1
    for (int kt = 0; kt < NT2 - 1; ++kt) {
        const int c = kt & 1, o = c ^ 1;
        const char* Ac = AsB + c * 32768;
        const char* Bc = BsB + c * 32768;
        LDA2(Ac, 0); LDB2(Bc, 0);
        STG_A2(o, 0, kt + 1);
        VMC(4); BARR; LGK0;
        MMAQ2(0, 0); BARR;
        LDB2(Bc, 1);
        STG_B2(o, 0, kt + 1);
        VMC(4); BARR; LGK0;
        MMAQ2(0, 1); BARR;
        LDA2(Ac, 1);
        STG_B2(o, 1, kt + 1);
        BARR; LGK0;
        MMAQ2(1, 1); BARR;
        LDB2(Bc, 0);
        STG_A2(o, 1, kt + 1);
        VMC(4); BARR; LGK0;
        MMAQ2(1, 0); BARR;
    }
    {
        const int c = (NT2 - 1) & 1;
        const char* Ac = AsB + c * 32768;
        const char* Bc = BsB + c * 32768;
        LDA2(Ac, 0); LDB2(Bc, 0); VMC(2); BARR; LGK0; MMAQ2(0, 0); BARR;
        LDB2(Bc, 1);              VMC(0); BARR; LGK0; MMAQ2(0, 1); BARR;
        LDA2(Ac, 1);                      BARR; LGK0; MMAQ2(1, 1); BARR;
        LDB2(Bc, 0);                            LGK0; MMAQ2(1, 0);
    }

#pragma unroll
    for (int m = 0; m < 8; ++m) {
        const int mq = m >> 2, i = m & 3;
        const int row0 = bm * 256 + mq * 128 + wr * 64 + i * 16 + quad * 4;
#pragma unroll
        for (int n = 0; n < 4; ++n) {
            const int nq = n >> 1, j = n & 1;
            const int col = nq * 128 + wc * 32 + j * 16 + l16;   // bn == 0
            const float bias = b2[col];
#pragma unroll
            for (int r = 0; r < 4; ++r) {
                const int row = row0 + r;
                if (row < N_NODES) {
                    const size_t idx = (size_t)row * NODE_F + col;
                    out[idx] = acc[m][n][r] + bias + x[idx];
                }
            }
        }
    }
#undef STG_A2
#undef STG_B2
#undef LDA2
#undef LDB2
#undef MMAQ2
}

extern "C" void kernel_launch(void* const* d_in, const int* in_sizes, int n_in,
                              void* d_out, int out_size, void* d_ws, size_t ws_size,
                              hipStream_t stream) {
    const float* x         = (const float*)d_in[0];
    const float* edge_attr = (const float*)d_in[1];
    const float* u         = (const float*)d_in[2];
    const float* W1        = (const float*)d_in[3];
    const float* b1        = (const float*)d_in[4];
    const float* W2        = (const float*)d_in[5];
    const float* b2        = (const float*)d_in[6];
    const int*   edge_index= (const int*)d_in[7];
    const int*   batch     = (const int*)d_in[8];
    float*       out       = (float*)d_out;

    char* ws = (char*)d_ws;
    bf16* H    = (bf16*)(ws + H_OFF);
    bf16* hid  = (bf16*)(ws + HID_OFF);
    bf16* W1t  = (bf16*)(ws + W1T_OFF);
    bf16* W2t  = (bf16*)(ws + W2T_OFF);
    int*  deg  = (int*)(ws + DEG_OFF);
    int*  start= (int*)(ws + START_OFF);
    int*  eids = (int*)(ws + EIDS_OFF);
    int*  rank = (int*)(ws + RANK_OFF);
    int*  bsum = (int*)(ws + BSUM_OFF);
    int*  boff = (int*)(ws + BOFF_OFF);

    const int* col = edge_index + N_EDGES;

    hipMemsetAsync(ws + DEG_OFF, 0, DEG_BYTES, stream);
    hist_rank_kernel<<<(N_EDGES + 255) / 256, 256, 0, stream>>>(col, deg, rank);
    scan_phase1<<<SCAN_BLOCKS, 256, 0, stream>>>(deg, start, bsum);
    scan_phase2<<<1, 256, 0, stream>>>(bsum, boff, start);
    place_kernel<<<(N_EDGES + 255) / 256, 256, 0, stream>>>(col, start, boff, rank, eids);
    build_h_kernel<<<M_PAD, 128, 0, stream>>>(x, edge_attr, u, batch, start, boff, eids, H);
    transpose2_kernel<<<896, 256, 0, stream>>>(W1, W1t, W2, W2t);
    gemm1_kernel<<<dim3(784), 512, 0, stream>>>(H, W1t, b1, hid);
    gemm2_kernel<<<dim3(196), 512, 0, stream>>>(hid, W2t, b2, x, out);
}